// Round 7
// baseline (348.966 us; speedup 1.0000x reference)
//
#include <hip/hip_runtime.h>
#include <math.h>

// ---------------------------------------------------------------------------
// GAT 3-layer net. CSR by dst built once per call (bucketed counting sort).
// R1-R8: register softmax, bf16 gather table, counting-sort CSR build.
// R9: all-bf16 dataflow + MFMA for layers 2/3 (mfma_f32_16x16x32_bf16).
// R10: layer-1 algebraic restructure (agg commutes with linear map; gather
//      raw X rows, 800KB L2-resident); 16-edge unroll in k_agg.
// R11: tail consolidation. Layer-3 k_agg emits bf16 (bufY dies); fused
//      pool+linear head (one WG per graph, binary search on sorted batch,
//      no gsum atomics/memset, bf16 input); k_aggx fused with the W1 tail
//      gemm (AX buffer dies); k_al1 folded into k_prep. 16 -> 12 dispatches.
// ---------------------------------------------------------------------------

#define BW 512          // nodes per bucket (power of 2)
#define PART_CHUNK 4096 // edges per WG in kb_part

typedef __attribute__((ext_vector_type(8))) short short8v;  // 8 bf16
typedef __attribute__((ext_vector_type(4))) float f32x4;

__device__ __forceinline__ float bflo(unsigned u) { return __uint_as_float(u << 16); }
__device__ __forceinline__ float bfhi(unsigned u) { return __uint_as_float(u & 0xffff0000u); }
// pack two f32 -> two bf16 (round-nearest-even), a in low half, b in high
__device__ __forceinline__ unsigned pk2bf(float a, float b) {
  unsigned ua = __float_as_uint(a); ua += 0x7fffu + ((ua >> 16) & 1u);
  unsigned ub = __float_as_uint(b); ub += 0x7fffu + ((ub >> 16) & 1u);
  return (ua >> 16) | (ub & 0xffff0000u);
}

// ---- CSR build, stage 1: per-bucket edge counts (LDS histogram) ----
__global__ __launch_bounds__(256) void kb_hist(const int* __restrict__ ei,
                                               int* __restrict__ bcnt,
                                               int E, int ET, int NB) {
  __shared__ int h[128];
  int tid = threadIdx.x;
  if (tid < 128) h[tid] = 0;
  __syncthreads();
  int stride = gridDim.x * 256;
  for (int i = blockIdx.x * 256 + tid; i < ET; i += stride) {
    int dst = (i < E) ? ei[E + i] : (i - E);
    atomicAdd(&h[dst >> 9], 1);
  }
  __syncthreads();
  if (tid < NB && h[tid] > 0) atomicAdd(&bcnt[tid], h[tid]);
}

// ---- stage 2: 1 WG exclusive-scans NB (<=128) bucket counts ----
__global__ __launch_bounds__(128) void kb_scan(const int* __restrict__ bcnt,
                                               int* __restrict__ bbase,
                                               int* __restrict__ bcur,
                                               int* __restrict__ rowp,
                                               int N, int ET, int NB) {
  __shared__ int sm[128];
  int t = threadIdx.x;
  int v = (t < NB) ? bcnt[t] : 0;
  sm[t] = v;
  __syncthreads();
  for (int off = 1; off < 128; off <<= 1) {
    int u = (t >= off) ? sm[t - off] : 0;
    __syncthreads();
    sm[t] += u;
    __syncthreads();
  }
  int pre = sm[t] - v;                  // exclusive
  if (t <= NB) bbase[t] = pre;          // bbase[NB] == ET
  if (t < NB) bcur[t] = pre;
  if (t == 0) rowp[N] = ET;
}

// ---- stage 3: partition edges into bucket runs (packed src<<9|dstlocal) ----
__global__ __launch_bounds__(256) void kb_part(const int* __restrict__ ei,
                                               int* __restrict__ bcur,
                                               int* __restrict__ bucketed,
                                               int E, int ET, int NB) {
  __shared__ int hist[128];
  __shared__ int runb[128];
  int tid = threadIdx.x;
  int base = blockIdx.x * PART_CHUNK;
  if (tid < 128) hist[tid] = 0;

  int sv[16], dv[16];
#pragma unroll
  for (int k = 0; k < 16; ++k) {
    int j = base + k * 256 + tid;
    int s = -1, d = 0;
    if (j < ET) {
      if (j < E) { s = ei[j]; d = ei[E + j]; }
      else       { s = j - E; d = j - E; }
    }
    sv[k] = s; dv[k] = d;
  }
  __syncthreads();
#pragma unroll
  for (int k = 0; k < 16; ++k)
    if (sv[k] >= 0) atomicAdd(&hist[dv[k] >> 9], 1);
  __syncthreads();
  if (tid < NB && hist[tid] > 0) runb[tid] = atomicAdd(&bcur[tid], hist[tid]);
  __syncthreads();
  if (tid < 128) hist[tid] = 0;   // reuse as within-run cursor
  __syncthreads();
#pragma unroll
  for (int k = 0; k < 16; ++k) {
    if (sv[k] >= 0) {
      int b = dv[k] >> 9;
      int off = atomicAdd(&hist[b], 1);
      bucketed[runb[b] + off] = (sv[k] << 9) | (dv[k] & (BW - 1));
    }
  }
}

// ---- stage 4: per-bucket counting sort -> rowp segment + csr window ----
__global__ __launch_bounds__(256) void kb_csr(const int* __restrict__ bucketed,
                                              const int* __restrict__ bbase,
                                              int* __restrict__ rowp,
                                              int* __restrict__ csr,
                                              int N) {
  __shared__ int h[512];
  __shared__ int sm[256];
  __shared__ int cur[512];
  int tid = threadIdx.x;
  int b = blockIdx.x;
  int cb = bbase[b], ce = bbase[b + 1];

  h[tid] = 0; h[tid + 256] = 0;
  __syncthreads();
  for (int j = cb + tid; j < ce; j += 256)
    atomicAdd(&h[bucketed[j] & (BW - 1)], 1);
  __syncthreads();
  int a0 = h[2 * tid], a1 = h[2 * tid + 1];
  int s = a0 + a1;
  sm[tid] = s;
  __syncthreads();
  for (int off = 1; off < 256; off <<= 1) {
    int u = (tid >= off) ? sm[tid - off] : 0;
    __syncthreads();
    sm[tid] += u;
    __syncthreads();
  }
  int pre = sm[tid] - s;                 // exclusive over pairs
  cur[2 * tid] = pre;
  cur[2 * tid + 1] = pre + a0;
  __syncthreads();
  int node0 = b * BW;
  for (int local = tid; local < BW; local += 256) {
    int node = node0 + local;
    if (node < N) rowp[node] = cb + cur[local];   // coalesced segment write
  }
  __syncthreads();
  for (int j = cb + tid; j < ce; j += 256) {
    int p = bucketed[j];
    int loc = p & (BW - 1);
    int pos = cb + atomicAdd(&cur[loc], 1);
    csr[pos] = (unsigned)p >> 9;          // confined to [cb,ce) window
  }
}

// ---- prep: bf16 col-major W2/W3 (blocks 0..63) + layer-1 al vecs (block 64):
//      wv[0..3] = W1@as1, wv[4..7] = W1@ad1 ----
__global__ __launch_bounds__(256) void k_prep(const float* __restrict__ W2,
                                              const float* __restrict__ W3,
                                              const float* __restrict__ W1,
                                              const float* __restrict__ as1,
                                              const float* __restrict__ ad1,
                                              unsigned short* __restrict__ Wcm2,
                                              unsigned short* __restrict__ Wcm3,
                                              float* __restrict__ wv) {
  if (blockIdx.x == 64) {
    int lane = threadIdx.x;
    if (lane >= 64) return;
    float2 a = *(const float2*)(as1 + lane * 2);
    float2 d = *(const float2*)(ad1 + lane * 2);
    float ps[4], pd[4];
#pragma unroll
    for (int k = 0; k < 4; ++k) {
      float2 w = *(const float2*)(W1 + k * 128 + lane * 2);
      ps[k] = w.x * a.x + w.y * a.y;
      pd[k] = w.x * d.x + w.y * d.y;
    }
    for (int off = 32; off; off >>= 1) {
#pragma unroll
      for (int k = 0; k < 4; ++k) {
        ps[k] += __shfl_xor(ps[k], off);
        pd[k] += __shfl_xor(pd[k], off);
      }
    }
    if (lane == 0) {
#pragma unroll
      for (int k = 0; k < 4; ++k) { wv[k] = ps[k]; wv[4 + k] = pd[k]; }
    }
    return;
  }
  int i = blockIdx.x * 256 + threadIdx.x;   // 16384 = 128*128
  if (i < 16384) {
    int k = i >> 7, n = i & 127;
    unsigned u = __float_as_uint(W2[i]); u += 0x7fffu + ((u >> 16) & 1u);
    Wcm2[n * 128 + k] = (unsigned short)(u >> 16);
    unsigned v = __float_as_uint(W3[i]); v += 0x7fffu + ((v >> 16) & 1u);
    Wcm3[n * 128 + k] = (unsigned short)(v >> 16);
  }
}

// ---- layer-1 per-node al: al_s = x . wv[0..3], al_d = x . wv[4..7] ----
__global__ __launch_bounds__(256) void k_alnode(const float* __restrict__ X,
                                                const float* __restrict__ wv,
                                                float* __restrict__ al_s,
                                                float* __restrict__ al_d, int N) {
  int i = blockIdx.x * 256 + threadIdx.x;
  if (i >= N) return;
  float4 xv = *(const float4*)(X + i * 4);
  al_s[i] = xv.x * wv[0] + xv.y * wv[1] + xv.z * wv[2] + xv.w * wv[3];
  al_d[i] = xv.x * wv[4] + xv.y * wv[5] + xv.z * wv[6] + xv.w * wv[7];
}

// ---- layer-1 fused agg + tail gemm: Y1 = relu((A@X)@W1 + b1) -> bf16 ----
// one wave per dst; lane-per-edge softmax over raw X (L2-resident, 16B rows);
// butterfly leaves the full AX row in every lane; each lane then computes
// its 2 output features and stores packed bf16. Fallback (deg>64): strided.
__global__ __launch_bounds__(256) void k_aggx1(const int* __restrict__ csr_src,
                                               const int* __restrict__ rowp,
                                               const float* __restrict__ al_s,
                                               const float* __restrict__ al_d,
                                               const float* __restrict__ X,
                                               const float* __restrict__ W,
                                               const float* __restrict__ bias,
                                               float* __restrict__ exw,
                                               unsigned* __restrict__ Ybf, int N) {
  int wid = threadIdx.x >> 6, lane = threadIdx.x & 63;
  int dst = blockIdx.x * 4 + wid;
  if (dst >= N) return;
  int beg = rowp[dst], end = rowp[dst + 1];
  int deg = end - beg;
  float ald = al_d[dst];
  float4 acc = {0.f, 0.f, 0.f, 0.f};

  if (deg <= 64) {
    int srcv = 0;
    float e = -INFINITY;
    if (lane < deg) {
      srcv = csr_src[beg + lane];
      e = al_s[srcv] + ald;
      e = (e > 0.f) ? e : 0.2f * e;
    }
    float m = e;
    for (int off = 32; off; off >>= 1) m = fmaxf(m, __shfl_xor(m, off));
    float av = (lane < deg) ? __expf(e - m) : 0.f;
    float den = av;
    for (int off = 32; off; off >>= 1) den += __shfl_xor(den, off);
    av *= 1.0f / (den + 1e-16f);
    float4 xv = {0.f, 0.f, 0.f, 0.f};
    if (lane < deg) xv = *(const float4*)(X + (size_t)srcv * 4);
    acc.x = av * xv.x; acc.y = av * xv.y; acc.z = av * xv.z; acc.w = av * xv.w;
  } else {
    float m = -INFINITY;
    for (int j = beg + lane; j < end; j += 64) {
      float e = al_s[csr_src[j]] + ald;
      e = (e > 0.f) ? e : 0.2f * e;
      exw[j] = e;
      m = fmaxf(m, e);
    }
    for (int off = 32; off; off >>= 1) m = fmaxf(m, __shfl_xor(m, off));
    float den = 0.f;
    for (int j = beg + lane; j < end; j += 64) {
      float ex = __expf(exw[j] - m);
      exw[j] = ex;
      den += ex;
    }
    for (int off = 32; off; off >>= 1) den += __shfl_xor(den, off);
    float inv = 1.0f / (den + 1e-16f);
    for (int j = beg + lane; j < end; j += 64) {
      int s = csr_src[j];
      float w = exw[j] * inv;
      float4 xv = *(const float4*)(X + (size_t)s * 4);
      acc.x += w * xv.x; acc.y += w * xv.y; acc.z += w * xv.z; acc.w += w * xv.w;
    }
  }
  for (int off = 32; off; off >>= 1) {
    acc.x += __shfl_xor(acc.x, off);
    acc.y += __shfl_xor(acc.y, off);
    acc.z += __shfl_xor(acc.z, off);
    acc.w += __shfl_xor(acc.w, off);
  }
  // tail gemm in-register: every lane holds full AX row
  int f = lane * 2;
  float2 w0 = *(const float2*)(W + f);
  float2 w1 = *(const float2*)(W + 128 + f);
  float2 w2 = *(const float2*)(W + 256 + f);
  float2 w3 = *(const float2*)(W + 384 + f);
  float2 bv = *(const float2*)(bias + f);
  float h0 = acc.x * w0.x + acc.y * w1.x + acc.z * w2.x + acc.w * w3.x + bv.x;
  float h1 = acc.x * w0.y + acc.y * w1.y + acc.z * w2.y + acc.w * w3.y + bv.y;
  h0 = fmaxf(h0, 0.f); h1 = fmaxf(h1, 0.f);
  Ybf[(size_t)dst * 64 + lane] = pk2bf(h0, h1);
}

// MFMA GEMM: Xbf [N,128] bf16 @ Wcm [128,128] bf16 (col-major) -> Hbf bf16,
// fused al epilogue. One wave per 16 rows; 8 col-frags x 4 k-tiles of
// mfma_f32_16x16x32_bf16. C layout: col=lane&15, row=(lane>>4)*4+reg.
__global__ __launch_bounds__(256) void k_gemm128mfma(
    const unsigned short* __restrict__ Xbf,
    const unsigned short* __restrict__ Wcm,
    const float* __restrict__ asv, const float* __restrict__ adv,
    unsigned* __restrict__ Hbf,
    float* __restrict__ al_s, float* __restrict__ al_d, int N) {
  int wid = threadIdx.x >> 6, lane = threadIdx.x & 63;
  int c = lane & 15, g = lane >> 4;
  int row0 = blockIdx.x * 64 + wid * 16;
  int arow = row0 + c;
  int arowc = (arow < N) ? arow : (N - 1);

  short8v a[4];
#pragma unroll
  for (int kt = 0; kt < 4; ++kt)
    a[kt] = *(const short8v*)(Xbf + (size_t)arowc * 128 + kt * 32 + g * 8);

  f32x4 acc[8];
#pragma unroll
  for (int f = 0; f < 8; ++f) acc[f] = (f32x4){0.f, 0.f, 0.f, 0.f};

#pragma unroll
  for (int f = 0; f < 8; ++f) {
    const unsigned short* wb = Wcm + (size_t)(f * 16 + c) * 128 + g * 8;
#pragma unroll
    for (int kt = 0; kt < 4; ++kt) {
      short8v b = *(const short8v*)(wb + kt * 32);
      acc[f] = __builtin_amdgcn_mfma_f32_16x16x32_bf16(a[kt], b, acc[f], 0, 0, 0);
    }
  }

  // al epilogue: ps/pd per row, reduce across the 16 col-lanes
  float ps[4] = {0.f, 0.f, 0.f, 0.f}, pd[4] = {0.f, 0.f, 0.f, 0.f};
#pragma unroll
  for (int f = 0; f < 8; ++f) {
    float as_c = asv[f * 16 + c], ad_c = adv[f * 16 + c];
#pragma unroll
    for (int j = 0; j < 4; ++j) { ps[j] += acc[f][j] * as_c; pd[j] += acc[f][j] * ad_c; }
  }
#pragma unroll
  for (int j = 0; j < 4; ++j) {
    for (int off = 1; off < 16; off <<= 1) {
      ps[j] += __shfl_xor(ps[j], off);
      pd[j] += __shfl_xor(pd[j], off);
    }
  }
  if (c == 0) {
#pragma unroll
    for (int j = 0; j < 4; ++j) {
      int r = row0 + g * 4 + j;
      if (r < N) { al_s[r] = ps[j]; al_d[r] = pd[j]; }
    }
  }

  // bf16 store: pair adjacent cols via shfl (uniform exec), even lanes store u32
#pragma unroll
  for (int f = 0; f < 8; ++f) {
#pragma unroll
    for (int j = 0; j < 4; ++j) {
      float partner = __shfl_xor(acc[f][j], 1);
      int r = row0 + g * 4 + j;
      if (((lane & 1) == 0) && r < N)
        Hbf[(size_t)r * 64 + f * 8 + (c >> 1)] = pk2bf(acc[f][j], partner);
    }
  }
}

// per-dst softmax + aggregation. one wave per dst. Always emits bf16 Y.
// Fast path (deg <= 64): lane owns one edge; softmax in registers;
//   gathers one uint4 (8 bf16) per lane per edge; 16-edge unroll.
//   Shfls exec-uniform. Fallback (deg > 64): 3-pass scratch.
__global__ __launch_bounds__(256) void k_agg(const int* __restrict__ csr_src,
                                             const int* __restrict__ rowp,
                                             const float* __restrict__ al_s,
                                             const float* __restrict__ al_d,
                                             const uint4* __restrict__ Hbf,
                                             const float* __restrict__ bias,
                                             float* __restrict__ exw,
                                             uint4* __restrict__ Ybf,
                                             int N, int relu) {
  int wid = threadIdx.x >> 6, lane = threadIdx.x & 63;
  int dst = blockIdx.x * 4 + wid;
  if (dst >= N) return;
  int beg = rowp[dst], end = rowp[dst + 1];
  int deg = end - beg;
  float ald = al_d[dst];

  int q = lane >> 4;       // quarter = edge offset within 4-edge group
  int l = lane & 15;       // feature lane: owns feats [l*8, l*8+8)
  float acc[8];
#pragma unroll
  for (int c = 0; c < 8; ++c) acc[c] = 0.f;

  if (deg <= 64) {
    // ---- register-resident softmax ----
    int srcv = 0;
    float e = -INFINITY;
    if (lane < deg) {
      srcv = csr_src[beg + lane];
      e = al_s[srcv] + ald;
      e = (e > 0.f) ? e : 0.2f * e;
    }
    float m = e;
    for (int off = 32; off; off >>= 1) m = fmaxf(m, __shfl_xor(m, off));
    float av = (lane < deg) ? __expf(e - m) : 0.f;
    float den = av;
    for (int off = 32; off; off >>= 1) den += __shfl_xor(den, off);
    av *= 1.0f / (den + 1e-16f);   // alpha, pre-normalized, in lane=edge

    int t = 0;
    for (; t + 16 <= deg; t += 16) {   // 16-edge unroll: 4 lines in flight
      int s0 = __shfl(srcv, t + q);
      int s1 = __shfl(srcv, t + 4 + q);
      int s2 = __shfl(srcv, t + 8 + q);
      int s3 = __shfl(srcv, t + 12 + q);
      float w0 = __shfl(av, t + q);
      float w1 = __shfl(av, t + 4 + q);
      float w2 = __shfl(av, t + 8 + q);
      float w3 = __shfl(av, t + 12 + q);
      uint4 v0 = Hbf[(size_t)s0 * 16 + l];
      uint4 v1 = Hbf[(size_t)s1 * 16 + l];
      uint4 v2 = Hbf[(size_t)s2 * 16 + l];
      uint4 v3 = Hbf[(size_t)s3 * 16 + l];
      acc[0] += w0 * bflo(v0.x) + w1 * bflo(v1.x) + w2 * bflo(v2.x) + w3 * bflo(v3.x);
      acc[1] += w0 * bfhi(v0.x) + w1 * bfhi(v1.x) + w2 * bfhi(v2.x) + w3 * bfhi(v3.x);
      acc[2] += w0 * bflo(v0.y) + w1 * bflo(v1.y) + w2 * bflo(v2.y) + w3 * bflo(v3.y);
      acc[3] += w0 * bfhi(v0.y) + w1 * bfhi(v1.y) + w2 * bfhi(v2.y) + w3 * bfhi(v3.y);
      acc[4] += w0 * bflo(v0.z) + w1 * bflo(v1.z) + w2 * bflo(v2.z) + w3 * bflo(v3.z);
      acc[5] += w0 * bfhi(v0.z) + w1 * bfhi(v1.z) + w2 * bfhi(v2.z) + w3 * bfhi(v3.z);
      acc[6] += w0 * bflo(v0.w) + w1 * bflo(v1.w) + w2 * bflo(v2.w) + w3 * bflo(v3.w);
      acc[7] += w0 * bfhi(v0.w) + w1 * bfhi(v1.w) + w2 * bfhi(v2.w) + w3 * bfhi(v3.w);
    }
    if (t + 8 <= deg) {
      int sA = __shfl(srcv, t + q);
      int sB = __shfl(srcv, t + 4 + q);
      float wA = __shfl(av, t + q);
      float wB = __shfl(av, t + 4 + q);
      uint4 va = Hbf[(size_t)sA * 16 + l];
      uint4 vb = Hbf[(size_t)sB * 16 + l];
      acc[0] += wA * bflo(va.x) + wB * bflo(vb.x);
      acc[1] += wA * bfhi(va.x) + wB * bfhi(vb.x);
      acc[2] += wA * bflo(va.y) + wB * bflo(vb.y);
      acc[3] += wA * bfhi(va.y) + wB * bfhi(vb.y);
      acc[4] += wA * bflo(va.z) + wB * bflo(vb.z);
      acc[5] += wA * bfhi(va.z) + wB * bfhi(vb.z);
      acc[6] += wA * bflo(va.w) + wB * bflo(vb.w);
      acc[7] += wA * bfhi(va.w) + wB * bfhi(vb.w);
      t += 8;
    }
    if (t + 4 <= deg) {                // uniform guard
      int sA = __shfl(srcv, t + q);
      float wA = __shfl(av, t + q);
      uint4 va = Hbf[(size_t)sA * 16 + l];
      acc[0] += wA * bflo(va.x); acc[1] += wA * bfhi(va.x);
      acc[2] += wA * bflo(va.y); acc[3] += wA * bfhi(va.y);
      acc[4] += wA * bflo(va.z); acc[5] += wA * bfhi(va.z);
      acc[6] += wA * bflo(va.w); acc[7] += wA * bfhi(va.w);
      t += 4;
    }
    {
      // tail: shfls hoisted OUT of the divergent guard (uniform exec)
      int sA = __shfl(srcv, t + q);
      float wA = __shfl(av, t + q);
      if (t + q < deg) {               // divergent: memory ops only
        uint4 va = Hbf[(size_t)sA * 16 + l];
        acc[0] += wA * bflo(va.x); acc[1] += wA * bfhi(va.x);
        acc[2] += wA * bflo(va.y); acc[3] += wA * bfhi(va.y);
        acc[4] += wA * bflo(va.z); acc[5] += wA * bfhi(va.z);
        acc[6] += wA * bflo(va.w); acc[7] += wA * bfhi(va.w);
      }
    }
  } else {
    // ---- generic fallback: 3-pass with per-edge scratch (bf16 gather) ----
    float m = -INFINITY;
    for (int j = beg + lane; j < end; j += 64) {
      float e = al_s[csr_src[j]] + ald;
      e = (e > 0.f) ? e : 0.2f * e;
      exw[j] = e;
      m = fmaxf(m, e);
    }
    for (int off = 32; off; off >>= 1) m = fmaxf(m, __shfl_xor(m, off));

    float den = 0.f;
    for (int j = beg + lane; j < end; j += 64) {
      float ex = __expf(exw[j] - m);
      exw[j] = ex;
      den += ex;
    }
    for (int off = 32; off; off >>= 1) den += __shfl_xor(den, off);
    float inv = 1.0f / (den + 1e-16f);

    for (int j = beg + q; j < end; j += 4) {
      int sA = csr_src[j];
      float wA = exw[j] * inv;
      uint4 va = Hbf[(size_t)sA * 16 + l];
      acc[0] += wA * bflo(va.x); acc[1] += wA * bfhi(va.x);
      acc[2] += wA * bflo(va.y); acc[3] += wA * bfhi(va.y);
      acc[4] += wA * bflo(va.z); acc[5] += wA * bfhi(va.z);
      acc[6] += wA * bflo(va.w); acc[7] += wA * bfhi(va.w);
    }
  }

#pragma unroll
  for (int c = 0; c < 8; ++c) {
    acc[c] += __shfl_xor(acc[c], 16);
    acc[c] += __shfl_xor(acc[c], 32);
  }
  if (q == 0) {
    float4 bv0 = *(const float4*)(bias + l * 8);
    float4 bv1 = *(const float4*)(bias + l * 8 + 4);
    float o0 = acc[0] + bv0.x, o1 = acc[1] + bv0.y, o2 = acc[2] + bv0.z, o3 = acc[3] + bv0.w;
    float o4 = acc[4] + bv1.x, o5 = acc[5] + bv1.y, o6 = acc[6] + bv1.z, o7 = acc[7] + bv1.w;
    if (relu) {
      o0 = fmaxf(o0, 0.f); o1 = fmaxf(o1, 0.f); o2 = fmaxf(o2, 0.f); o3 = fmaxf(o3, 0.f);
      o4 = fmaxf(o4, 0.f); o5 = fmaxf(o5, 0.f); o6 = fmaxf(o6, 0.f); o7 = fmaxf(o7, 0.f);
    }
    uint4 pb;
    pb.x = pk2bf(o0, o1); pb.y = pk2bf(o2, o3);
    pb.z = pk2bf(o4, o5); pb.w = pk2bf(o6, o7);
    Ybf[(size_t)dst * 16 + l] = pb;
  }
}

// ---- fused global mean pool + linear head: one WG per graph ----
// batch sorted: binary-search [beg,end); 4 waves accumulate bf16 rows in
// f32 (lane owns feature pair 2*lane,2*lane+1); LDS combine; wave 0 applies
// mean and the 128->2 head; lane 0 writes the 2 outputs.
__global__ __launch_bounds__(256) void k_poolhead(const unsigned* __restrict__ Ybf,
                                                  const int* __restrict__ batch,
                                                  const float* __restrict__ Wlin,
                                                  const float* __restrict__ blin,
                                                  float* __restrict__ out, int N) {
  __shared__ float gs[4][128];
  __shared__ int bounds[2];
  int tid = threadIdx.x, wid = tid >> 6, lane = tid & 63;
  int g = blockIdx.x;
  if (tid < 2) {
    int target = g + tid;            // lower_bound(batch, target)
    int lo = 0, hi = N;
    while (lo < hi) { int mid = (lo + hi) >> 1; if (batch[mid] < target) lo = mid + 1; else hi = mid; }
    bounds[tid] = lo;
  }
  __syncthreads();
  int beg = bounds[0], end = bounds[1];
  float2 a = {0.f, 0.f};
  for (int n = beg + wid; n < end; n += 4) {
    unsigned u = Ybf[(size_t)n * 64 + lane];
    a.x += bflo(u); a.y += bfhi(u);
  }
  gs[wid][lane * 2] = a.x;
  gs[wid][lane * 2 + 1] = a.y;
  __syncthreads();
  if (wid == 0) {
    int k0 = lane * 2, k1 = k0 + 1;
    float inv = 1.0f / fmaxf((float)(end - beg), 1.0f);
    float s0 = (gs[0][k0] + gs[1][k0] + gs[2][k0] + gs[3][k0]) * inv;
    float s1 = (gs[0][k1] + gs[1][k1] + gs[2][k1] + gs[3][k1]) * inv;
    float p0 = s0 * Wlin[k0 * 2] + s1 * Wlin[k1 * 2];
    float p1 = s0 * Wlin[k0 * 2 + 1] + s1 * Wlin[k1 * 2 + 1];
    for (int off = 32; off; off >>= 1) {
      p0 += __shfl_xor(p0, off);
      p1 += __shfl_xor(p1, off);
    }
    if (lane == 0) {
      out[g * 2 + 0] = blin[0] + p0;
      out[g * 2 + 1] = blin[1] + p1;
    }
  }
}

extern "C" void kernel_launch(void* const* d_in, const int* in_sizes, int n_in,
                              void* d_out, int out_size, void* d_ws, size_t ws_size,
                              hipStream_t stream) {
  const float* x    = (const float*)d_in[0];
  const int*   ei   = (const int*)d_in[1];
  const int*   batch= (const int*)d_in[2];
  const float* W1   = (const float*)d_in[3];
  const float* as1  = (const float*)d_in[4];
  const float* ad1  = (const float*)d_in[5];
  const float* b1   = (const float*)d_in[6];
  const float* W2   = (const float*)d_in[7];
  const float* as2  = (const float*)d_in[8];
  const float* ad2  = (const float*)d_in[9];
  const float* b2   = (const float*)d_in[10];
  const float* W3   = (const float*)d_in[11];
  const float* as3  = (const float*)d_in[12];
  const float* ad3  = (const float*)d_in[13];
  const float* b3   = (const float*)d_in[14];
  const float* Wlin = (const float*)d_in[15];
  const float* blin = (const float*)d_in[16];

  int N = in_sizes[0] / 4;
  int E = in_sizes[1] / 2;
  int ET = E + N;
  int NB = (N + BW - 1) / BW;   // buckets (<=128 for N<=65536)

  char* ws = (char*)d_ws;
  unsigned* bfA = (unsigned*)ws; ws += (size_t)N * 64 * 4;   // bf16 H table
  unsigned* bfB = (unsigned*)ws; ws += (size_t)N * 64 * 4;   // bf16 Y table
  float* al_s = (float*)ws; ws += (size_t)N * 4;
  float* al_d = (float*)ws; ws += (size_t)N * 4;
  float* wv   = (float*)ws; ws += (size_t)64 * 4;            // layer-1 al vecs
  int* rowp   = (int*)ws;   ws += (size_t)(N + 1) * 4;
  int* csr    = (int*)ws;   ws += (size_t)ET * 4;
  float* exw  = (float*)ws; ws += (size_t)ET * 4;
  int* bucketed = (int*)ws; ws += (size_t)ET * 4;
  int* bcnt   = (int*)ws;   ws += (size_t)128 * 4;
  int* bbase  = (int*)ws;   ws += (size_t)132 * 4;
  int* bcur   = (int*)ws;   ws += (size_t)128 * 4;
  unsigned short* wcm2 = (unsigned short*)ws; ws += (size_t)128 * 128 * 2;
  unsigned short* wcm3 = (unsigned short*)ws; ws += (size_t)128 * 128 * 2;

  hipMemsetAsync(bcnt, 0, (size_t)128 * 4, stream);

  // CSR build (bucketed counting sort) + W prep/al1
  kb_hist<<<256, 256, 0, stream>>>(ei, bcnt, E, ET, NB);
  kb_scan<<<1, 128, 0, stream>>>(bcnt, bbase, bcur, rowp, N, ET, NB);
  kb_part<<<(ET + PART_CHUNK - 1) / PART_CHUNK, 256, 0, stream>>>(ei, bcur, bucketed, E, ET, NB);
  kb_csr <<<NB, 256, 0, stream>>>(bucketed, bbase, rowp, csr, N);
  k_prep <<<65, 256, 0, stream>>>(W2, W3, W1, as1, ad1, wcm2, wcm3, wv);

  int nb4 = (N + 3) / 4;
  int nb64 = (N + 63) / 64;
  // layer 1: al from X dots; fused gather-X + W1 tail
  k_alnode<<<(N + 255) / 256, 256, 0, stream>>>(x, wv, al_s, al_d, N);
  k_aggx1 <<<nb4, 256, 0, stream>>>(csr, rowp, al_s, al_d, x, W1, b1, exw, bfB, N);
  // layer 2
  k_gemm128mfma<<<nb64, 256, 0, stream>>>((const unsigned short*)bfB, wcm2, as2, ad2, bfA, al_s, al_d, N);
  k_agg        <<<nb4, 256, 0, stream>>>(csr, rowp, al_s, al_d, (const uint4*)bfA, b2, exw, (uint4*)bfB, N, 1);
  // layer 3
  k_gemm128mfma<<<nb64, 256, 0, stream>>>((const unsigned short*)bfB, wcm3, as3, ad3, bfA, al_s, al_d, N);
  k_agg        <<<nb4, 256, 0, stream>>>(csr, rowp, al_s, al_d, (const uint4*)bfA, b3, exw, (uint4*)bfB, N, 0);

  // fused global mean pool + linear head (one WG per graph)
  k_poolhead<<<64, 256, 0, stream>>>(bfB, batch, Wlin, blin, (float*)d_out, N);
}

// Round 8
// 317.705 us; speedup vs baseline: 1.0984x; 1.0984x over previous
//
#include <hip/hip_runtime.h>
#include <math.h>

// ---------------------------------------------------------------------------
// GAT 3-layer net. CSR by dst built once per call (bucketed counting sort).
// R1-R8: register softmax, bf16 gather table, counting-sort CSR build.
// R9: all-bf16 dataflow + MFMA for layers 2/3 (mfma_f32_16x16x32_bf16).
// R10: layer-1 algebraic restructure (agg commutes with linear map; gather
//      raw X rows, 800KB L2-resident); 16-edge unroll in k_agg.
// R11: layer-3 k_agg emits bf16; k_aggx fused with W1 tail; k_al1 in k_prep.
// R12: FIX R11's pool. One-WG-per-graph head was 64 WGs = 2% occupancy,
//      latency-bound at 64us (12x the old pool). Restore run-length k_pool
//      (1024 waves, sorted batch, one atomic flush per segment boundary)
//      reading the bf16 Y table, + tiny k_final. Fusion that collapses
//      parallelism below ~1 wave/CU loses more to latency than it saves.
// ---------------------------------------------------------------------------

#define BW 512          // nodes per bucket (power of 2)
#define PART_CHUNK 4096 // edges per WG in kb_part

typedef __attribute__((ext_vector_type(8))) short short8v;  // 8 bf16
typedef __attribute__((ext_vector_type(4))) float f32x4;

__device__ __forceinline__ float bflo(unsigned u) { return __uint_as_float(u << 16); }
__device__ __forceinline__ float bfhi(unsigned u) { return __uint_as_float(u & 0xffff0000u); }
// pack two f32 -> two bf16 (round-nearest-even), a in low half, b in high
__device__ __forceinline__ unsigned pk2bf(float a, float b) {
  unsigned ua = __float_as_uint(a); ua += 0x7fffu + ((ua >> 16) & 1u);
  unsigned ub = __float_as_uint(b); ub += 0x7fffu + ((ub >> 16) & 1u);
  return (ua >> 16) | (ub & 0xffff0000u);
}

// ---- CSR build, stage 1: per-bucket edge counts (LDS histogram) ----
__global__ __launch_bounds__(256) void kb_hist(const int* __restrict__ ei,
                                               int* __restrict__ bcnt,
                                               int E, int ET, int NB) {
  __shared__ int h[128];
  int tid = threadIdx.x;
  if (tid < 128) h[tid] = 0;
  __syncthreads();
  int stride = gridDim.x * 256;
  for (int i = blockIdx.x * 256 + tid; i < ET; i += stride) {
    int dst = (i < E) ? ei[E + i] : (i - E);
    atomicAdd(&h[dst >> 9], 1);
  }
  __syncthreads();
  if (tid < NB && h[tid] > 0) atomicAdd(&bcnt[tid], h[tid]);
}

// ---- stage 2: 1 WG exclusive-scans NB (<=128) bucket counts ----
__global__ __launch_bounds__(128) void kb_scan(const int* __restrict__ bcnt,
                                               int* __restrict__ bbase,
                                               int* __restrict__ bcur,
                                               int* __restrict__ rowp,
                                               int N, int ET, int NB) {
  __shared__ int sm[128];
  int t = threadIdx.x;
  int v = (t < NB) ? bcnt[t] : 0;
  sm[t] = v;
  __syncthreads();
  for (int off = 1; off < 128; off <<= 1) {
    int u = (t >= off) ? sm[t - off] : 0;
    __syncthreads();
    sm[t] += u;
    __syncthreads();
  }
  int pre = sm[t] - v;                  // exclusive
  if (t <= NB) bbase[t] = pre;          // bbase[NB] == ET
  if (t < NB) bcur[t] = pre;
  if (t == 0) rowp[N] = ET;
}

// ---- stage 3: partition edges into bucket runs (packed src<<9|dstlocal) ----
__global__ __launch_bounds__(256) void kb_part(const int* __restrict__ ei,
                                               int* __restrict__ bcur,
                                               int* __restrict__ bucketed,
                                               int E, int ET, int NB) {
  __shared__ int hist[128];
  __shared__ int runb[128];
  int tid = threadIdx.x;
  int base = blockIdx.x * PART_CHUNK;
  if (tid < 128) hist[tid] = 0;

  int sv[16], dv[16];
#pragma unroll
  for (int k = 0; k < 16; ++k) {
    int j = base + k * 256 + tid;
    int s = -1, d = 0;
    if (j < ET) {
      if (j < E) { s = ei[j]; d = ei[E + j]; }
      else       { s = j - E; d = j - E; }
    }
    sv[k] = s; dv[k] = d;
  }
  __syncthreads();
#pragma unroll
  for (int k = 0; k < 16; ++k)
    if (sv[k] >= 0) atomicAdd(&hist[dv[k] >> 9], 1);
  __syncthreads();
  if (tid < NB && hist[tid] > 0) runb[tid] = atomicAdd(&bcur[tid], hist[tid]);
  __syncthreads();
  if (tid < 128) hist[tid] = 0;   // reuse as within-run cursor
  __syncthreads();
#pragma unroll
  for (int k = 0; k < 16; ++k) {
    if (sv[k] >= 0) {
      int b = dv[k] >> 9;
      int off = atomicAdd(&hist[b], 1);
      bucketed[runb[b] + off] = (sv[k] << 9) | (dv[k] & (BW - 1));
    }
  }
}

// ---- stage 4: per-bucket counting sort -> rowp segment + csr window ----
__global__ __launch_bounds__(256) void kb_csr(const int* __restrict__ bucketed,
                                              const int* __restrict__ bbase,
                                              int* __restrict__ rowp,
                                              int* __restrict__ csr,
                                              int N) {
  __shared__ int h[512];
  __shared__ int sm[256];
  __shared__ int cur[512];
  int tid = threadIdx.x;
  int b = blockIdx.x;
  int cb = bbase[b], ce = bbase[b + 1];

  h[tid] = 0; h[tid + 256] = 0;
  __syncthreads();
  for (int j = cb + tid; j < ce; j += 256)
    atomicAdd(&h[bucketed[j] & (BW - 1)], 1);
  __syncthreads();
  int a0 = h[2 * tid], a1 = h[2 * tid + 1];
  int s = a0 + a1;
  sm[tid] = s;
  __syncthreads();
  for (int off = 1; off < 256; off <<= 1) {
    int u = (tid >= off) ? sm[tid - off] : 0;
    __syncthreads();
    sm[tid] += u;
    __syncthreads();
  }
  int pre = sm[tid] - s;                 // exclusive over pairs
  cur[2 * tid] = pre;
  cur[2 * tid + 1] = pre + a0;
  __syncthreads();
  int node0 = b * BW;
  for (int local = tid; local < BW; local += 256) {
    int node = node0 + local;
    if (node < N) rowp[node] = cb + cur[local];   // coalesced segment write
  }
  __syncthreads();
  for (int j = cb + tid; j < ce; j += 256) {
    int p = bucketed[j];
    int loc = p & (BW - 1);
    int pos = cb + atomicAdd(&cur[loc], 1);
    csr[pos] = (unsigned)p >> 9;          // confined to [cb,ce) window
  }
}

// ---- prep: bf16 col-major W2/W3 (blocks 0..63) + layer-1 al vecs (block 64):
//      wv[0..3] = W1@as1, wv[4..7] = W1@ad1 ----
__global__ __launch_bounds__(256) void k_prep(const float* __restrict__ W2,
                                              const float* __restrict__ W3,
                                              const float* __restrict__ W1,
                                              const float* __restrict__ as1,
                                              const float* __restrict__ ad1,
                                              unsigned short* __restrict__ Wcm2,
                                              unsigned short* __restrict__ Wcm3,
                                              float* __restrict__ wv) {
  if (blockIdx.x == 64) {
    int lane = threadIdx.x;
    if (lane >= 64) return;
    float2 a = *(const float2*)(as1 + lane * 2);
    float2 d = *(const float2*)(ad1 + lane * 2);
    float ps[4], pd[4];
#pragma unroll
    for (int k = 0; k < 4; ++k) {
      float2 w = *(const float2*)(W1 + k * 128 + lane * 2);
      ps[k] = w.x * a.x + w.y * a.y;
      pd[k] = w.x * d.x + w.y * d.y;
    }
    for (int off = 32; off; off >>= 1) {
#pragma unroll
      for (int k = 0; k < 4; ++k) {
        ps[k] += __shfl_xor(ps[k], off);
        pd[k] += __shfl_xor(pd[k], off);
      }
    }
    if (lane == 0) {
#pragma unroll
      for (int k = 0; k < 4; ++k) { wv[k] = ps[k]; wv[4 + k] = pd[k]; }
    }
    return;
  }
  int i = blockIdx.x * 256 + threadIdx.x;   // 16384 = 128*128
  if (i < 16384) {
    int k = i >> 7, n = i & 127;
    unsigned u = __float_as_uint(W2[i]); u += 0x7fffu + ((u >> 16) & 1u);
    Wcm2[n * 128 + k] = (unsigned short)(u >> 16);
    unsigned v = __float_as_uint(W3[i]); v += 0x7fffu + ((v >> 16) & 1u);
    Wcm3[n * 128 + k] = (unsigned short)(v >> 16);
  }
}

// ---- layer-1 per-node al: al_s = x . wv[0..3], al_d = x . wv[4..7] ----
__global__ __launch_bounds__(256) void k_alnode(const float* __restrict__ X,
                                                const float* __restrict__ wv,
                                                float* __restrict__ al_s,
                                                float* __restrict__ al_d, int N) {
  int i = blockIdx.x * 256 + threadIdx.x;
  if (i >= N) return;
  float4 xv = *(const float4*)(X + i * 4);
  al_s[i] = xv.x * wv[0] + xv.y * wv[1] + xv.z * wv[2] + xv.w * wv[3];
  al_d[i] = xv.x * wv[4] + xv.y * wv[5] + xv.z * wv[6] + xv.w * wv[7];
}

// ---- layer-1 fused agg + tail gemm: Y1 = relu((A@X)@W1 + b1) -> bf16 ----
// one wave per dst; lane-per-edge softmax over raw X (L2-resident, 16B rows);
// butterfly leaves the full AX row in every lane; each lane then computes
// its 2 output features and stores packed bf16. Fallback (deg>64): strided.
__global__ __launch_bounds__(256) void k_aggx1(const int* __restrict__ csr_src,
                                               const int* __restrict__ rowp,
                                               const float* __restrict__ al_s,
                                               const float* __restrict__ al_d,
                                               const float* __restrict__ X,
                                               const float* __restrict__ W,
                                               const float* __restrict__ bias,
                                               float* __restrict__ exw,
                                               unsigned* __restrict__ Ybf, int N) {
  int wid = threadIdx.x >> 6, lane = threadIdx.x & 63;
  int dst = blockIdx.x * 4 + wid;
  if (dst >= N) return;
  int beg = rowp[dst], end = rowp[dst + 1];
  int deg = end - beg;
  float ald = al_d[dst];
  float4 acc = {0.f, 0.f, 0.f, 0.f};

  if (deg <= 64) {
    int srcv = 0;
    float e = -INFINITY;
    if (lane < deg) {
      srcv = csr_src[beg + lane];
      e = al_s[srcv] + ald;
      e = (e > 0.f) ? e : 0.2f * e;
    }
    float m = e;
    for (int off = 32; off; off >>= 1) m = fmaxf(m, __shfl_xor(m, off));
    float av = (lane < deg) ? __expf(e - m) : 0.f;
    float den = av;
    for (int off = 32; off; off >>= 1) den += __shfl_xor(den, off);
    av *= 1.0f / (den + 1e-16f);
    float4 xv = {0.f, 0.f, 0.f, 0.f};
    if (lane < deg) xv = *(const float4*)(X + (size_t)srcv * 4);
    acc.x = av * xv.x; acc.y = av * xv.y; acc.z = av * xv.z; acc.w = av * xv.w;
  } else {
    float m = -INFINITY;
    for (int j = beg + lane; j < end; j += 64) {
      float e = al_s[csr_src[j]] + ald;
      e = (e > 0.f) ? e : 0.2f * e;
      exw[j] = e;
      m = fmaxf(m, e);
    }
    for (int off = 32; off; off >>= 1) m = fmaxf(m, __shfl_xor(m, off));
    float den = 0.f;
    for (int j = beg + lane; j < end; j += 64) {
      float ex = __expf(exw[j] - m);
      exw[j] = ex;
      den += ex;
    }
    for (int off = 32; off; off >>= 1) den += __shfl_xor(den, off);
    float inv = 1.0f / (den + 1e-16f);
    for (int j = beg + lane; j < end; j += 64) {
      int s = csr_src[j];
      float w = exw[j] * inv;
      float4 xv = *(const float4*)(X + (size_t)s * 4);
      acc.x += w * xv.x; acc.y += w * xv.y; acc.z += w * xv.z; acc.w += w * xv.w;
    }
  }
  for (int off = 32; off; off >>= 1) {
    acc.x += __shfl_xor(acc.x, off);
    acc.y += __shfl_xor(acc.y, off);
    acc.z += __shfl_xor(acc.z, off);
    acc.w += __shfl_xor(acc.w, off);
  }
  // tail gemm in-register: every lane holds full AX row
  int f = lane * 2;
  float2 w0 = *(const float2*)(W + f);
  float2 w1 = *(const float2*)(W + 128 + f);
  float2 w2 = *(const float2*)(W + 256 + f);
  float2 w3 = *(const float2*)(W + 384 + f);
  float2 bv = *(const float2*)(bias + f);
  float h0 = acc.x * w0.x + acc.y * w1.x + acc.z * w2.x + acc.w * w3.x + bv.x;
  float h1 = acc.x * w0.y + acc.y * w1.y + acc.z * w2.y + acc.w * w3.y + bv.y;
  h0 = fmaxf(h0, 0.f); h1 = fmaxf(h1, 0.f);
  Ybf[(size_t)dst * 64 + lane] = pk2bf(h0, h1);
}

// MFMA GEMM: Xbf [N,128] bf16 @ Wcm [128,128] bf16 (col-major) -> Hbf bf16,
// fused al epilogue. One wave per 16 rows; 8 col-frags x 4 k-tiles of
// mfma_f32_16x16x32_bf16. C layout: col=lane&15, row=(lane>>4)*4+reg.
__global__ __launch_bounds__(256) void k_gemm128mfma(
    const unsigned short* __restrict__ Xbf,
    const unsigned short* __restrict__ Wcm,
    const float* __restrict__ asv, const float* __restrict__ adv,
    unsigned* __restrict__ Hbf,
    float* __restrict__ al_s, float* __restrict__ al_d, int N) {
  int wid = threadIdx.x >> 6, lane = threadIdx.x & 63;
  int c = lane & 15, g = lane >> 4;
  int row0 = blockIdx.x * 64 + wid * 16;
  int arow = row0 + c;
  int arowc = (arow < N) ? arow : (N - 1);

  short8v a[4];
#pragma unroll
  for (int kt = 0; kt < 4; ++kt)
    a[kt] = *(const short8v*)(Xbf + (size_t)arowc * 128 + kt * 32 + g * 8);

  f32x4 acc[8];
#pragma unroll
  for (int f = 0; f < 8; ++f) acc[f] = (f32x4){0.f, 0.f, 0.f, 0.f};

#pragma unroll
  for (int f = 0; f < 8; ++f) {
    const unsigned short* wb = Wcm + (size_t)(f * 16 + c) * 128 + g * 8;
#pragma unroll
    for (int kt = 0; kt < 4; ++kt) {
      short8v b = *(const short8v*)(wb + kt * 32);
      acc[f] = __builtin_amdgcn_mfma_f32_16x16x32_bf16(a[kt], b, acc[f], 0, 0, 0);
    }
  }

  // al epilogue: ps/pd per row, reduce across the 16 col-lanes
  float ps[4] = {0.f, 0.f, 0.f, 0.f}, pd[4] = {0.f, 0.f, 0.f, 0.f};
#pragma unroll
  for (int f = 0; f < 8; ++f) {
    float as_c = asv[f * 16 + c], ad_c = adv[f * 16 + c];
#pragma unroll
    for (int j = 0; j < 4; ++j) { ps[j] += acc[f][j] * as_c; pd[j] += acc[f][j] * ad_c; }
  }
#pragma unroll
  for (int j = 0; j < 4; ++j) {
    for (int off = 1; off < 16; off <<= 1) {
      ps[j] += __shfl_xor(ps[j], off);
      pd[j] += __shfl_xor(pd[j], off);
    }
  }
  if (c == 0) {
#pragma unroll
    for (int j = 0; j < 4; ++j) {
      int r = row0 + g * 4 + j;
      if (r < N) { al_s[r] = ps[j]; al_d[r] = pd[j]; }
    }
  }

  // bf16 store: pair adjacent cols via shfl (uniform exec), even lanes store u32
#pragma unroll
  for (int f = 0; f < 8; ++f) {
#pragma unroll
    for (int j = 0; j < 4; ++j) {
      float partner = __shfl_xor(acc[f][j], 1);
      int r = row0 + g * 4 + j;
      if (((lane & 1) == 0) && r < N)
        Hbf[(size_t)r * 64 + f * 8 + (c >> 1)] = pk2bf(acc[f][j], partner);
    }
  }
}

// per-dst softmax + aggregation. one wave per dst. Always emits bf16 Y.
// Fast path (deg <= 64): lane owns one edge; softmax in registers;
//   gathers one uint4 (8 bf16) per lane per edge; 16-edge unroll.
//   Shfls exec-uniform. Fallback (deg > 64): 3-pass scratch.
__global__ __launch_bounds__(256) void k_agg(const int* __restrict__ csr_src,
                                             const int* __restrict__ rowp,
                                             const float* __restrict__ al_s,
                                             const float* __restrict__ al_d,
                                             const uint4* __restrict__ Hbf,
                                             const float* __restrict__ bias,
                                             float* __restrict__ exw,
                                             uint4* __restrict__ Ybf,
                                             int N, int relu) {
  int wid = threadIdx.x >> 6, lane = threadIdx.x & 63;
  int dst = blockIdx.x * 4 + wid;
  if (dst >= N) return;
  int beg = rowp[dst], end = rowp[dst + 1];
  int deg = end - beg;
  float ald = al_d[dst];

  int q = lane >> 4;       // quarter = edge offset within 4-edge group
  int l = lane & 15;       // feature lane: owns feats [l*8, l*8+8)
  float acc[8];
#pragma unroll
  for (int c = 0; c < 8; ++c) acc[c] = 0.f;

  if (deg <= 64) {
    // ---- register-resident softmax ----
    int srcv = 0;
    float e = -INFINITY;
    if (lane < deg) {
      srcv = csr_src[beg + lane];
      e = al_s[srcv] + ald;
      e = (e > 0.f) ? e : 0.2f * e;
    }
    float m = e;
    for (int off = 32; off; off >>= 1) m = fmaxf(m, __shfl_xor(m, off));
    float av = (lane < deg) ? __expf(e - m) : 0.f;
    float den = av;
    for (int off = 32; off; off >>= 1) den += __shfl_xor(den, off);
    av *= 1.0f / (den + 1e-16f);   // alpha, pre-normalized, in lane=edge

    int t = 0;
    for (; t + 16 <= deg; t += 16) {   // 16-edge unroll: 4 lines in flight
      int s0 = __shfl(srcv, t + q);
      int s1 = __shfl(srcv, t + 4 + q);
      int s2 = __shfl(srcv, t + 8 + q);
      int s3 = __shfl(srcv, t + 12 + q);
      float w0 = __shfl(av, t + q);
      float w1 = __shfl(av, t + 4 + q);
      float w2 = __shfl(av, t + 8 + q);
      float w3 = __shfl(av, t + 12 + q);
      uint4 v0 = Hbf[(size_t)s0 * 16 + l];
      uint4 v1 = Hbf[(size_t)s1 * 16 + l];
      uint4 v2 = Hbf[(size_t)s2 * 16 + l];
      uint4 v3 = Hbf[(size_t)s3 * 16 + l];
      acc[0] += w0 * bflo(v0.x) + w1 * bflo(v1.x) + w2 * bflo(v2.x) + w3 * bflo(v3.x);
      acc[1] += w0 * bfhi(v0.x) + w1 * bfhi(v1.x) + w2 * bfhi(v2.x) + w3 * bfhi(v3.x);
      acc[2] += w0 * bflo(v0.y) + w1 * bflo(v1.y) + w2 * bflo(v2.y) + w3 * bflo(v3.y);
      acc[3] += w0 * bfhi(v0.y) + w1 * bfhi(v1.y) + w2 * bfhi(v2.y) + w3 * bfhi(v3.y);
      acc[4] += w0 * bflo(v0.z) + w1 * bflo(v1.z) + w2 * bflo(v2.z) + w3 * bflo(v3.z);
      acc[5] += w0 * bfhi(v0.z) + w1 * bfhi(v1.z) + w2 * bfhi(v2.z) + w3 * bfhi(v3.z);
      acc[6] += w0 * bflo(v0.w) + w1 * bflo(v1.w) + w2 * bflo(v2.w) + w3 * bflo(v3.w);
      acc[7] += w0 * bfhi(v0.w) + w1 * bfhi(v1.w) + w2 * bfhi(v2.w) + w3 * bfhi(v3.w);
    }
    if (t + 8 <= deg) {
      int sA = __shfl(srcv, t + q);
      int sB = __shfl(srcv, t + 4 + q);
      float wA = __shfl(av, t + q);
      float wB = __shfl(av, t + 4 + q);
      uint4 va = Hbf[(size_t)sA * 16 + l];
      uint4 vb = Hbf[(size_t)sB * 16 + l];
      acc[0] += wA * bflo(va.x) + wB * bflo(vb.x);
      acc[1] += wA * bfhi(va.x) + wB * bfhi(vb.x);
      acc[2] += wA * bflo(va.y) + wB * bflo(vb.y);
      acc[3] += wA * bfhi(va.y) + wB * bfhi(vb.y);
      acc[4] += wA * bflo(va.z) + wB * bflo(vb.z);
      acc[5] += wA * bfhi(va.z) + wB * bfhi(vb.z);
      acc[6] += wA * bflo(va.w) + wB * bflo(vb.w);
      acc[7] += wA * bfhi(va.w) + wB * bfhi(vb.w);
      t += 8;
    }
    if (t + 4 <= deg) {                // uniform guard
      int sA = __shfl(srcv, t + q);
      float wA = __shfl(av, t + q);
      uint4 va = Hbf[(size_t)sA * 16 + l];
      acc[0] += wA * bflo(va.x); acc[1] += wA * bfhi(va.x);
      acc[2] += wA * bflo(va.y); acc[3] += wA * bfhi(va.y);
      acc[4] += wA * bflo(va.z); acc[5] += wA * bfhi(va.z);
      acc[6] += wA * bflo(va.w); acc[7] += wA * bfhi(va.w);
      t += 4;
    }
    {
      // tail: shfls hoisted OUT of the divergent guard (uniform exec)
      int sA = __shfl(srcv, t + q);
      float wA = __shfl(av, t + q);
      if (t + q < deg) {               // divergent: memory ops only
        uint4 va = Hbf[(size_t)sA * 16 + l];
        acc[0] += wA * bflo(va.x); acc[1] += wA * bfhi(va.x);
        acc[2] += wA * bflo(va.y); acc[3] += wA * bfhi(va.y);
        acc[4] += wA * bflo(va.z); acc[5] += wA * bfhi(va.z);
        acc[6] += wA * bflo(va.w); acc[7] += wA * bfhi(va.w);
      }
    }
  } else {
    // ---- generic fallback: 3-pass with per-edge scratch (bf16 gather) ----
    float m = -INFINITY;
    for (int j = beg + lane; j < end; j += 64) {
      float e = al_s[csr_src[j]] + ald;
      e = (e > 0.f) ? e : 0.2f * e;
      exw[j] = e;
      m = fmaxf(m, e);
    }
    for (int off = 32; off; off >>= 1) m = fmaxf(m, __shfl_xor(m, off));

    float den = 0.f;
    for (int j = beg + lane; j < end; j += 64) {
      float ex = __expf(exw[j] - m);
      exw[j] = ex;
      den += ex;
    }
    for (int off = 32; off; off >>= 1) den += __shfl_xor(den, off);
    float inv = 1.0f / (den + 1e-16f);

    for (int j = beg + q; j < end; j += 4) {
      int sA = csr_src[j];
      float wA = exw[j] * inv;
      uint4 va = Hbf[(size_t)sA * 16 + l];
      acc[0] += wA * bflo(va.x); acc[1] += wA * bfhi(va.x);
      acc[2] += wA * bflo(va.y); acc[3] += wA * bfhi(va.y);
      acc[4] += wA * bflo(va.z); acc[5] += wA * bfhi(va.z);
      acc[6] += wA * bflo(va.w); acc[7] += wA * bfhi(va.w);
    }
  }

#pragma unroll
  for (int c = 0; c < 8; ++c) {
    acc[c] += __shfl_xor(acc[c], 16);
    acc[c] += __shfl_xor(acc[c], 32);
  }
  if (q == 0) {
    float4 bv0 = *(const float4*)(bias + l * 8);
    float4 bv1 = *(const float4*)(bias + l * 8 + 4);
    float o0 = acc[0] + bv0.x, o1 = acc[1] + bv0.y, o2 = acc[2] + bv0.z, o3 = acc[3] + bv0.w;
    float o4 = acc[4] + bv1.x, o5 = acc[5] + bv1.y, o6 = acc[6] + bv1.z, o7 = acc[7] + bv1.w;
    if (relu) {
      o0 = fmaxf(o0, 0.f); o1 = fmaxf(o1, 0.f); o2 = fmaxf(o2, 0.f); o3 = fmaxf(o3, 0.f);
      o4 = fmaxf(o4, 0.f); o5 = fmaxf(o5, 0.f); o6 = fmaxf(o6, 0.f); o7 = fmaxf(o7, 0.f);
    }
    uint4 pb;
    pb.x = pk2bf(o0, o1); pb.y = pk2bf(o2, o3);
    pb.z = pk2bf(o4, o5); pb.w = pk2bf(o6, o7);
    Ybf[(size_t)dst * 16 + l] = pb;
  }
}

// run-length pooling over sorted batch, bf16 input (lane owns feats 2l,2l+1)
__global__ __launch_bounds__(256) void k_pool(const unsigned* __restrict__ Ybf,
                                              const int* __restrict__ batch,
                                              float* __restrict__ gsum,
                                              float* __restrict__ gcnt,
                                              int N, int nwaves) {
  int gw = (blockIdx.x * 256 + threadIdx.x) >> 6;
  int lane = threadIdx.x & 63;
  int chunk = (N + nwaves - 1) / nwaves;
  int beg = gw * chunk;
  int end = beg + chunk; if (end > N) end = N;
  if (beg >= end) return;

  int curg = batch[beg];
  float2 acc = {0.f, 0.f};
  int cnt = 0;
  for (int n = beg; n < end; ++n) {
    int g = batch[n];
    if (g != curg) {
      atomicAdd(&gsum[curg * 128 + lane * 2], acc.x);
      atomicAdd(&gsum[curg * 128 + lane * 2 + 1], acc.y);
      if (lane == 0) atomicAdd(&gcnt[curg], (float)cnt);
      acc.x = 0.f; acc.y = 0.f; cnt = 0; curg = g;
    }
    unsigned u = Ybf[(size_t)n * 64 + lane];
    acc.x += bflo(u); acc.y += bfhi(u);
    ++cnt;
  }
  atomicAdd(&gsum[curg * 128 + lane * 2], acc.x);
  atomicAdd(&gsum[curg * 128 + lane * 2 + 1], acc.y);
  if (lane == 0) atomicAdd(&gcnt[curg], (float)cnt);
}

__global__ __launch_bounds__(128) void k_final(const float* __restrict__ gsum,
                                               const float* __restrict__ gcnt,
                                               const float* __restrict__ Wlin,
                                               const float* __restrict__ blin,
                                               float* __restrict__ out) {
  int t = threadIdx.x;  // 128 threads: (g, c) pairs
  int g = t >> 1, c = t & 1;
  float inv = 1.0f / fmaxf(gcnt[g], 1.0f);
  float acc = blin[c];
  for (int k = 0; k < 128; ++k) acc += gsum[g * 128 + k] * inv * Wlin[k * 2 + c];
  out[g * 2 + c] = acc;
}

extern "C" void kernel_launch(void* const* d_in, const int* in_sizes, int n_in,
                              void* d_out, int out_size, void* d_ws, size_t ws_size,
                              hipStream_t stream) {
  const float* x    = (const float*)d_in[0];
  const int*   ei   = (const int*)d_in[1];
  const int*   batch= (const int*)d_in[2];
  const float* W1   = (const float*)d_in[3];
  const float* as1  = (const float*)d_in[4];
  const float* ad1  = (const float*)d_in[5];
  const float* b1   = (const float*)d_in[6];
  const float* W2   = (const float*)d_in[7];
  const float* as2  = (const float*)d_in[8];
  const float* ad2  = (const float*)d_in[9];
  const float* b2   = (const float*)d_in[10];
  const float* W3   = (const float*)d_in[11];
  const float* as3  = (const float*)d_in[12];
  const float* ad3  = (const float*)d_in[13];
  const float* b3   = (const float*)d_in[14];
  const float* Wlin = (const float*)d_in[15];
  const float* blin = (const float*)d_in[16];

  int N = in_sizes[0] / 4;
  int E = in_sizes[1] / 2;
  int ET = E + N;
  int NB = (N + BW - 1) / BW;   // buckets (<=128 for N<=65536)

  char* ws = (char*)d_ws;
  unsigned* bfA = (unsigned*)ws; ws += (size_t)N * 64 * 4;   // bf16 H table
  unsigned* bfB = (unsigned*)ws; ws += (size_t)N * 64 * 4;   // bf16 Y table
  float* al_s = (float*)ws; ws += (size_t)N * 4;
  float* al_d = (float*)ws; ws += (size_t)N * 4;
  float* wv   = (float*)ws; ws += (size_t)64 * 4;            // layer-1 al vecs
  float* gsum = (float*)ws; ws += (size_t)64 * 128 * 4;
  float* gcnt = (float*)ws; ws += (size_t)64 * 4;
  int* rowp   = (int*)ws;   ws += (size_t)(N + 1) * 4;
  int* csr    = (int*)ws;   ws += (size_t)ET * 4;
  float* exw  = (float*)ws; ws += (size_t)ET * 4;
  int* bucketed = (int*)ws; ws += (size_t)ET * 4;
  int* bcnt   = (int*)ws;   ws += (size_t)128 * 4;
  int* bbase  = (int*)ws;   ws += (size_t)132 * 4;
  int* bcur   = (int*)ws;   ws += (size_t)128 * 4;
  unsigned short* wcm2 = (unsigned short*)ws; ws += (size_t)128 * 128 * 2;
  unsigned short* wcm3 = (unsigned short*)ws; ws += (size_t)128 * 128 * 2;

  hipMemsetAsync(bcnt, 0, (size_t)128 * 4, stream);
  hipMemsetAsync(gsum, 0, (size_t)(64 * 128 + 64) * 4, stream);  // gsum + gcnt

  // CSR build (bucketed counting sort) + W prep/al1
  kb_hist<<<256, 256, 0, stream>>>(ei, bcnt, E, ET, NB);
  kb_scan<<<1, 128, 0, stream>>>(bcnt, bbase, bcur, rowp, N, ET, NB);
  kb_part<<<(ET + PART_CHUNK - 1) / PART_CHUNK, 256, 0, stream>>>(ei, bcur, bucketed, E, ET, NB);
  kb_csr <<<NB, 256, 0, stream>>>(bucketed, bbase, rowp, csr, N);
  k_prep <<<65, 256, 0, stream>>>(W2, W3, W1, as1, ad1, wcm2, wcm3, wv);

  int nb4 = (N + 3) / 4;
  int nb64 = (N + 63) / 64;
  // layer 1: al from X dots; fused gather-X + W1 tail
  k_alnode<<<(N + 255) / 256, 256, 0, stream>>>(x, wv, al_s, al_d, N);
  k_aggx1 <<<nb4, 256, 0, stream>>>(csr, rowp, al_s, al_d, x, W1, b1, exw, bfB, N);
  // layer 2
  k_gemm128mfma<<<nb64, 256, 0, stream>>>((const unsigned short*)bfB, wcm2, as2, ad2, bfA, al_s, al_d, N);
  k_agg        <<<nb4, 256, 0, stream>>>(csr, rowp, al_s, al_d, (const uint4*)bfA, b2, exw, (uint4*)bfB, N, 1);
  // layer 3
  k_gemm128mfma<<<nb64, 256, 0, stream>>>((const unsigned short*)bfB, wcm3, as3, ad3, bfA, al_s, al_d, N);
  k_agg        <<<nb4, 256, 0, stream>>>(csr, rowp, al_s, al_d, (const uint4*)bfA, b3, exw, (uint4*)bfB, N, 0);

  // run-length pool (1024 waves) + linear head
  k_pool <<<256, 256, 0, stream>>>(bfB, batch, gsum, gcnt, N, 1024);
  k_final<<<1, 128, 0, stream>>>(gsum, gcnt, Wlin, blin, (float*)d_out);
}

// Round 9
// 312.545 us; speedup vs baseline: 1.1165x; 1.0165x over previous
//
#include <hip/hip_runtime.h>
#include <math.h>

// ---------------------------------------------------------------------------
// GAT 3-layer net. CSR by dst built once per call (bucketed counting sort).
// R1-R8: register softmax, bf16 gather table, counting-sort CSR build.
// R9: all-bf16 dataflow + MFMA for layers 2/3 (mfma_f32_16x16x32_bf16).
// R10: layer-1 algebraic restructure (gather raw X rows, L2-resident).
// R11: layer-3 bf16 out; k_aggx+W1-tail fusion; k_al1 in k_prep.
// R12: run-length k_pool restored (R11's 64-WG pool was latency-bound).
// R13: overhead round. (a) kb_hist -> per-WG partials (no bcnt memset, no
//      global atomics), kb_scan reduces; (b) gsum/gcnt zeroed by spare
//      k_prep blocks (memset dispatch dies); (c) k_alnode folded into
//      k_aggx1 (al computed from the already-loaded x rows, bit-identical);
//      (d) nontemporal stores for all bf16-table writes -> gather table
//      keeps more of the 4MB per-XCD L2. 15 -> 12 dispatches.
// ---------------------------------------------------------------------------

#define BW 512          // nodes per bucket (power of 2)
#define PART_CHUNK 4096 // edges per WG in kb_part
#define HIST_WGS 256    // kb_hist grid (fixed; partial buffer sized to match)

typedef __attribute__((ext_vector_type(8))) short short8v;  // 8 bf16
typedef __attribute__((ext_vector_type(4))) float f32x4;
typedef __attribute__((ext_vector_type(4))) unsigned uint4v;

__device__ __forceinline__ float bflo(unsigned u) { return __uint_as_float(u << 16); }
__device__ __forceinline__ float bfhi(unsigned u) { return __uint_as_float(u & 0xffff0000u); }
// pack two f32 -> two bf16 (round-nearest-even), a in low half, b in high
__device__ __forceinline__ unsigned pk2bf(float a, float b) {
  unsigned ua = __float_as_uint(a); ua += 0x7fffu + ((ua >> 16) & 1u);
  unsigned ub = __float_as_uint(b); ub += 0x7fffu + ((ub >> 16) & 1u);
  return (ua >> 16) | (ub & 0xffff0000u);
}

// ---- CSR build, stage 1: per-bucket counts -> per-WG partials (no atomics,
//      no memset: every WG writes all 128 slots) ----
__global__ __launch_bounds__(256) void kb_hist(const int* __restrict__ ei,
                                               int* __restrict__ bpart,
                                               int E, int ET) {
  __shared__ int h[128];
  int tid = threadIdx.x;
  if (tid < 128) h[tid] = 0;
  __syncthreads();
  int stride = HIST_WGS * 256;
  for (int i = blockIdx.x * 256 + tid; i < ET; i += stride) {
    int dst = (i < E) ? ei[E + i] : (i - E);
    atomicAdd(&h[dst >> 9], 1);
  }
  __syncthreads();
  if (tid < 128) bpart[blockIdx.x * 128 + tid] = h[tid];
}

// ---- stage 2: 1 WG reduces partials + exclusive-scans NB (<=128) buckets ----
__global__ __launch_bounds__(128) void kb_scan(const int* __restrict__ bpart,
                                               int* __restrict__ bbase,
                                               int* __restrict__ bcur,
                                               int* __restrict__ rowp,
                                               int N, int ET, int NB) {
  __shared__ int sm[128];
  int t = threadIdx.x;
  int v = 0;
  for (int w = 0; w < HIST_WGS; ++w) v += bpart[w * 128 + t];  // coalesced
  if (t >= NB) v = 0;
  sm[t] = v;
  __syncthreads();
  for (int off = 1; off < 128; off <<= 1) {
    int u = (t >= off) ? sm[t - off] : 0;
    __syncthreads();
    sm[t] += u;
    __syncthreads();
  }
  int pre = sm[t] - v;                  // exclusive
  if (t <= NB) bbase[t] = pre;          // bbase[NB] == ET
  if (t < NB) bcur[t] = pre;
  if (t == 0) rowp[N] = ET;
}

// ---- stage 3: partition edges into bucket runs (packed src<<9|dstlocal) ----
__global__ __launch_bounds__(256) void kb_part(const int* __restrict__ ei,
                                               int* __restrict__ bcur,
                                               int* __restrict__ bucketed,
                                               int E, int ET, int NB) {
  __shared__ int hist[128];
  __shared__ int runb[128];
  int tid = threadIdx.x;
  int base = blockIdx.x * PART_CHUNK;
  if (tid < 128) hist[tid] = 0;

  int sv[16], dv[16];
#pragma unroll
  for (int k = 0; k < 16; ++k) {
    int j = base + k * 256 + tid;
    int s = -1, d = 0;
    if (j < ET) {
      if (j < E) { s = ei[j]; d = ei[E + j]; }
      else       { s = j - E; d = j - E; }
    }
    sv[k] = s; dv[k] = d;
  }
  __syncthreads();
#pragma unroll
  for (int k = 0; k < 16; ++k)
    if (sv[k] >= 0) atomicAdd(&hist[dv[k] >> 9], 1);
  __syncthreads();
  if (tid < NB && hist[tid] > 0) runb[tid] = atomicAdd(&bcur[tid], hist[tid]);
  __syncthreads();
  if (tid < 128) hist[tid] = 0;   // reuse as within-run cursor
  __syncthreads();
#pragma unroll
  for (int k = 0; k < 16; ++k) {
    if (sv[k] >= 0) {
      int b = dv[k] >> 9;
      int off = atomicAdd(&hist[b], 1);
      bucketed[runb[b] + off] = (sv[k] << 9) | (dv[k] & (BW - 1));
    }
  }
}

// ---- stage 4: per-bucket counting sort -> rowp segment + csr window ----
__global__ __launch_bounds__(256) void kb_csr(const int* __restrict__ bucketed,
                                              const int* __restrict__ bbase,
                                              int* __restrict__ rowp,
                                              int* __restrict__ csr,
                                              int N) {
  __shared__ int h[512];
  __shared__ int sm[256];
  __shared__ int cur[512];
  int tid = threadIdx.x;
  int b = blockIdx.x;
  int cb = bbase[b], ce = bbase[b + 1];

  h[tid] = 0; h[tid + 256] = 0;
  __syncthreads();
  for (int j = cb + tid; j < ce; j += 256)
    atomicAdd(&h[bucketed[j] & (BW - 1)], 1);
  __syncthreads();
  int a0 = h[2 * tid], a1 = h[2 * tid + 1];
  int s = a0 + a1;
  sm[tid] = s;
  __syncthreads();
  for (int off = 1; off < 256; off <<= 1) {
    int u = (tid >= off) ? sm[tid - off] : 0;
    __syncthreads();
    sm[tid] += u;
    __syncthreads();
  }
  int pre = sm[tid] - s;                 // exclusive over pairs
  cur[2 * tid] = pre;
  cur[2 * tid + 1] = pre + a0;
  __syncthreads();
  int node0 = b * BW;
  for (int local = tid; local < BW; local += 256) {
    int node = node0 + local;
    if (node < N) rowp[node] = cb + cur[local];   // coalesced segment write
  }
  __syncthreads();
  for (int j = cb + tid; j < ce; j += 256) {
    int p = bucketed[j];
    int loc = p & (BW - 1);
    int pos = cb + atomicAdd(&cur[loc], 1);
    csr[pos] = (unsigned)p >> 9;          // confined to [cb,ce) window
  }
}

// ---- prep: blocks 0..63 bf16 col-major W2/W3; block 64 layer-1 al vecs
//      (wv[0..3]=W1@as1, wv[4..7]=W1@ad1); blocks 65..97 zero gsum+gcnt ----
__global__ __launch_bounds__(256) void k_prep(const float* __restrict__ W2,
                                              const float* __restrict__ W3,
                                              const float* __restrict__ W1,
                                              const float* __restrict__ as1,
                                              const float* __restrict__ ad1,
                                              unsigned short* __restrict__ Wcm2,
                                              unsigned short* __restrict__ Wcm3,
                                              float* __restrict__ wv,
                                              float* __restrict__ gsum) {
  if (blockIdx.x >= 65) {   // zero gsum (8192) + gcnt (64), contiguous
    int idx = (blockIdx.x - 65) * 256 + threadIdx.x;
    if (idx < 64 * 128 + 64) gsum[idx] = 0.f;
    return;
  }
  if (blockIdx.x == 64) {
    int lane = threadIdx.x;
    if (lane >= 64) return;
    float2 a = *(const float2*)(as1 + lane * 2);
    float2 d = *(const float2*)(ad1 + lane * 2);
    float ps[4], pd[4];
#pragma unroll
    for (int k = 0; k < 4; ++k) {
      float2 w = *(const float2*)(W1 + k * 128 + lane * 2);
      ps[k] = w.x * a.x + w.y * a.y;
      pd[k] = w.x * d.x + w.y * d.y;
    }
    for (int off = 32; off; off >>= 1) {
#pragma unroll
      for (int k = 0; k < 4; ++k) {
        ps[k] += __shfl_xor(ps[k], off);
        pd[k] += __shfl_xor(pd[k], off);
      }
    }
    if (lane == 0) {
#pragma unroll
      for (int k = 0; k < 4; ++k) { wv[k] = ps[k]; wv[4 + k] = pd[k]; }
    }
    return;
  }
  int i = blockIdx.x * 256 + threadIdx.x;   // 16384 = 128*128
  if (i < 16384) {
    int k = i >> 7, n = i & 127;
    unsigned u = __float_as_uint(W2[i]); u += 0x7fffu + ((u >> 16) & 1u);
    Wcm2[n * 128 + k] = (unsigned short)(u >> 16);
    unsigned v = __float_as_uint(W3[i]); v += 0x7fffu + ((v >> 16) & 1u);
    Wcm3[n * 128 + k] = (unsigned short)(v >> 16);
  }
}

// ---- layer-1 fused agg + tail gemm: Y1 = relu((A@X)@W1 + b1) -> bf16 ----
// al computed in-register from the already-loaded x rows (al = x . wv).
// one wave per dst; lane-per-edge softmax; butterfly leaves full AX row in
// every lane; lane computes its 2 output features. Fallback (deg>64): strided.
__global__ __launch_bounds__(256) void k_aggx1(const int* __restrict__ csr_src,
                                               const int* __restrict__ rowp,
                                               const float* __restrict__ wv,
                                               const float* __restrict__ X,
                                               const float* __restrict__ W,
                                               const float* __restrict__ bias,
                                               float* __restrict__ exw,
                                               unsigned* __restrict__ Ybf, int N) {
  int wid = threadIdx.x >> 6, lane = threadIdx.x & 63;
  int dst = blockIdx.x * 4 + wid;
  if (dst >= N) return;
  int beg = rowp[dst], end = rowp[dst + 1];
  int deg = end - beg;
  float wvs0 = wv[0], wvs1 = wv[1], wvs2 = wv[2], wvs3 = wv[3];
  float4 xd = *(const float4*)(X + (size_t)dst * 4);   // broadcast line
  float ald = xd.x * wv[4] + xd.y * wv[5] + xd.z * wv[6] + xd.w * wv[7];
  float4 acc = {0.f, 0.f, 0.f, 0.f};

  if (deg <= 64) {
    int srcv = 0;
    float e = -INFINITY;
    float4 xv = {0.f, 0.f, 0.f, 0.f};
    if (lane < deg) {
      srcv = csr_src[beg + lane];
      xv = *(const float4*)(X + (size_t)srcv * 4);
      float als = xv.x * wvs0 + xv.y * wvs1 + xv.z * wvs2 + xv.w * wvs3;
      e = als + ald;
      e = (e > 0.f) ? e : 0.2f * e;
    }
    float m = e;
    for (int off = 32; off; off >>= 1) m = fmaxf(m, __shfl_xor(m, off));
    float av = (lane < deg) ? __expf(e - m) : 0.f;
    float den = av;
    for (int off = 32; off; off >>= 1) den += __shfl_xor(den, off);
    av *= 1.0f / (den + 1e-16f);
    acc.x = av * xv.x; acc.y = av * xv.y; acc.z = av * xv.z; acc.w = av * xv.w;
  } else {
    float m = -INFINITY;
    for (int j = beg + lane; j < end; j += 64) {
      int s = csr_src[j];
      float4 xv = *(const float4*)(X + (size_t)s * 4);
      float e = xv.x * wvs0 + xv.y * wvs1 + xv.z * wvs2 + xv.w * wvs3 + ald;
      e = (e > 0.f) ? e : 0.2f * e;
      exw[j] = e;
      m = fmaxf(m, e);
    }
    for (int off = 32; off; off >>= 1) m = fmaxf(m, __shfl_xor(m, off));
    float den = 0.f;
    for (int j = beg + lane; j < end; j += 64) {
      float ex = __expf(exw[j] - m);
      exw[j] = ex;
      den += ex;
    }
    for (int off = 32; off; off >>= 1) den += __shfl_xor(den, off);
    float inv = 1.0f / (den + 1e-16f);
    for (int j = beg + lane; j < end; j += 64) {
      int s = csr_src[j];
      float w = exw[j] * inv;
      float4 xv = *(const float4*)(X + (size_t)s * 4);
      acc.x += w * xv.x; acc.y += w * xv.y; acc.z += w * xv.z; acc.w += w * xv.w;
    }
  }
  for (int off = 32; off; off >>= 1) {
    acc.x += __shfl_xor(acc.x, off);
    acc.y += __shfl_xor(acc.y, off);
    acc.z += __shfl_xor(acc.z, off);
    acc.w += __shfl_xor(acc.w, off);
  }
  // tail gemm in-register: every lane holds full AX row
  int f = lane * 2;
  float2 w0 = *(const float2*)(W + f);
  float2 w1 = *(const float2*)(W + 128 + f);
  float2 w2 = *(const float2*)(W + 256 + f);
  float2 w3 = *(const float2*)(W + 384 + f);
  float2 bv = *(const float2*)(bias + f);
  float h0 = acc.x * w0.x + acc.y * w1.x + acc.z * w2.x + acc.w * w3.x + bv.x;
  float h1 = acc.x * w0.y + acc.y * w1.y + acc.z * w2.y + acc.w * w3.y + bv.y;
  h0 = fmaxf(h0, 0.f); h1 = fmaxf(h1, 0.f);
  __builtin_nontemporal_store(pk2bf(h0, h1), Ybf + (size_t)dst * 64 + lane);
}

// MFMA GEMM: Xbf [N,128] bf16 @ Wcm [128,128] bf16 (col-major) -> Hbf bf16,
// fused al epilogue. One wave per 16 rows; 8 col-frags x 4 k-tiles of
// mfma_f32_16x16x32_bf16. C layout: col=lane&15, row=(lane>>4)*4+reg.
__global__ __launch_bounds__(256) void k_gemm128mfma(
    const unsigned short* __restrict__ Xbf,
    const unsigned short* __restrict__ Wcm,
    const float* __restrict__ asv, const float* __restrict__ adv,
    unsigned* __restrict__ Hbf,
    float* __restrict__ al_s, float* __restrict__ al_d, int N) {
  int wid = threadIdx.x >> 6, lane = threadIdx.x & 63;
  int c = lane & 15, g = lane >> 4;
  int row0 = blockIdx.x * 64 + wid * 16;
  int arow = row0 + c;
  int arowc = (arow < N) ? arow : (N - 1);

  short8v a[4];
#pragma unroll
  for (int kt = 0; kt < 4; ++kt)
    a[kt] = *(const short8v*)(Xbf + (size_t)arowc * 128 + kt * 32 + g * 8);

  f32x4 acc[8];
#pragma unroll
  for (int f = 0; f < 8; ++f) acc[f] = (f32x4){0.f, 0.f, 0.f, 0.f};

#pragma unroll
  for (int f = 0; f < 8; ++f) {
    const unsigned short* wb = Wcm + (size_t)(f * 16 + c) * 128 + g * 8;
#pragma unroll
    for (int kt = 0; kt < 4; ++kt) {
      short8v b = *(const short8v*)(wb + kt * 32);
      acc[f] = __builtin_amdgcn_mfma_f32_16x16x32_bf16(a[kt], b, acc[f], 0, 0, 0);
    }
  }

  // al epilogue: ps/pd per row, reduce across the 16 col-lanes
  float ps[4] = {0.f, 0.f, 0.f, 0.f}, pd[4] = {0.f, 0.f, 0.f, 0.f};
#pragma unroll
  for (int f = 0; f < 8; ++f) {
    float as_c = asv[f * 16 + c], ad_c = adv[f * 16 + c];
#pragma unroll
    for (int j = 0; j < 4; ++j) { ps[j] += acc[f][j] * as_c; pd[j] += acc[f][j] * ad_c; }
  }
#pragma unroll
  for (int j = 0; j < 4; ++j) {
    for (int off = 1; off < 16; off <<= 1) {
      ps[j] += __shfl_xor(ps[j], off);
      pd[j] += __shfl_xor(pd[j], off);
    }
  }
  if (c == 0) {
#pragma unroll
    for (int j = 0; j < 4; ++j) {
      int r = row0 + g * 4 + j;
      if (r < N) { al_s[r] = ps[j]; al_d[r] = pd[j]; }
    }
  }

  // bf16 store: pair adjacent cols via shfl (uniform exec), even lanes store u32
#pragma unroll
  for (int f = 0; f < 8; ++f) {
#pragma unroll
    for (int j = 0; j < 4; ++j) {
      float partner = __shfl_xor(acc[f][j], 1);
      int r = row0 + g * 4 + j;
      if (((lane & 1) == 0) && r < N)
        __builtin_nontemporal_store(pk2bf(acc[f][j], partner),
                                    Hbf + (size_t)r * 64 + f * 8 + (c >> 1));
    }
  }
}

// per-dst softmax + aggregation. one wave per dst. Always emits bf16 Y (nt).
// Fast path (deg <= 64): lane owns one edge; softmax in registers;
//   gathers one uint4 (8 bf16) per lane per edge; 16-edge unroll.
//   Shfls exec-uniform. Fallback (deg > 64): 3-pass scratch.
__global__ __launch_bounds__(256) void k_agg(const int* __restrict__ csr_src,
                                             const int* __restrict__ rowp,
                                             const float* __restrict__ al_s,
                                             const float* __restrict__ al_d,
                                             const uint4* __restrict__ Hbf,
                                             const float* __restrict__ bias,
                                             float* __restrict__ exw,
                                             unsigned* __restrict__ Ybf,
                                             int N, int relu) {
  int wid = threadIdx.x >> 6, lane = threadIdx.x & 63;
  int dst = blockIdx.x * 4 + wid;
  if (dst >= N) return;
  int beg = rowp[dst], end = rowp[dst + 1];
  int deg = end - beg;
  float ald = al_d[dst];

  int q = lane >> 4;       // quarter = edge offset within 4-edge group
  int l = lane & 15;       // feature lane: owns feats [l*8, l*8+8)
  float acc[8];
#pragma unroll
  for (int c = 0; c < 8; ++c) acc[c] = 0.f;

  if (deg <= 64) {
    // ---- register-resident softmax ----
    int srcv = 0;
    float e = -INFINITY;
    if (lane < deg) {
      srcv = csr_src[beg + lane];
      e = al_s[srcv] + ald;
      e = (e > 0.f) ? e : 0.2f * e;
    }
    float m = e;
    for (int off = 32; off; off >>= 1) m = fmaxf(m, __shfl_xor(m, off));
    float av = (lane < deg) ? __expf(e - m) : 0.f;
    float den = av;
    for (int off = 32; off; off >>= 1) den += __shfl_xor(den, off);
    av *= 1.0f / (den + 1e-16f);   // alpha, pre-normalized, in lane=edge

    int t = 0;
    for (; t + 16 <= deg; t += 16) {   // 16-edge unroll: 4 lines in flight
      int s0 = __shfl(srcv, t + q);
      int s1 = __shfl(srcv, t + 4 + q);
      int s2 = __shfl(srcv, t + 8 + q);
      int s3 = __shfl(srcv, t + 12 + q);
      float w0 = __shfl(av, t + q);
      float w1 = __shfl(av, t + 4 + q);
      float w2 = __shfl(av, t + 8 + q);
      float w3 = __shfl(av, t + 12 + q);
      uint4 v0 = Hbf[(size_t)s0 * 16 + l];
      uint4 v1 = Hbf[(size_t)s1 * 16 + l];
      uint4 v2 = Hbf[(size_t)s2 * 16 + l];
      uint4 v3 = Hbf[(size_t)s3 * 16 + l];
      acc[0] += w0 * bflo(v0.x) + w1 * bflo(v1.x) + w2 * bflo(v2.x) + w3 * bflo(v3.x);
      acc[1] += w0 * bfhi(v0.x) + w1 * bfhi(v1.x) + w2 * bfhi(v2.x) + w3 * bfhi(v3.x);
      acc[2] += w0 * bflo(v0.y) + w1 * bflo(v1.y) + w2 * bflo(v2.y) + w3 * bflo(v3.y);
      acc[3] += w0 * bfhi(v0.y) + w1 * bfhi(v1.y) + w2 * bfhi(v2.y) + w3 * bfhi(v3.y);
      acc[4] += w0 * bflo(v0.z) + w1 * bflo(v1.z) + w2 * bflo(v2.z) + w3 * bflo(v3.z);
      acc[5] += w0 * bfhi(v0.z) + w1 * bfhi(v1.z) + w2 * bfhi(v2.z) + w3 * bfhi(v3.z);
      acc[6] += w0 * bflo(v0.w) + w1 * bflo(v1.w) + w2 * bflo(v2.w) + w3 * bflo(v3.w);
      acc[7] += w0 * bfhi(v0.w) + w1 * bfhi(v1.w) + w2 * bfhi(v2.w) + w3 * bfhi(v3.w);
    }
    if (t + 8 <= deg) {
      int sA = __shfl(srcv, t + q);
      int sB = __shfl(srcv, t + 4 + q);
      float wA = __shfl(av, t + q);
      float wB = __shfl(av, t + 4 + q);
      uint4 va = Hbf[(size_t)sA * 16 + l];
      uint4 vb = Hbf[(size_t)sB * 16 + l];
      acc[0] += wA * bflo(va.x) + wB * bflo(vb.x);
      acc[1] += wA * bfhi(va.x) + wB * bfhi(vb.x);
      acc[2] += wA * bflo(va.y) + wB * bflo(vb.y);
      acc[3] += wA * bfhi(va.y) + wB * bfhi(vb.y);
      acc[4] += wA * bflo(va.z) + wB * bflo(vb.z);
      acc[5] += wA * bfhi(va.z) + wB * bfhi(vb.z);
      acc[6] += wA * bflo(va.w) + wB * bflo(vb.w);
      acc[7] += wA * bfhi(va.w) + wB * bfhi(vb.w);
      t += 8;
    }
    if (t + 4 <= deg) {                // uniform guard
      int sA = __shfl(srcv, t + q);
      float wA = __shfl(av, t + q);
      uint4 va = Hbf[(size_t)sA * 16 + l];
      acc[0] += wA * bflo(va.x); acc[1] += wA * bfhi(va.x);
      acc[2] += wA * bflo(va.y); acc[3] += wA * bfhi(va.y);
      acc[4] += wA * bflo(va.z); acc[5] += wA * bfhi(va.z);
      acc[6] += wA * bflo(va.w); acc[7] += wA * bfhi(va.w);
      t += 4;
    }
    {
      // tail: shfls hoisted OUT of the divergent guard (uniform exec)
      int sA = __shfl(srcv, t + q);
      float wA = __shfl(av, t + q);
      if (t + q < deg) {               // divergent: memory ops only
        uint4 va = Hbf[(size_t)sA * 16 + l];
        acc[0] += wA * bflo(va.x); acc[1] += wA * bfhi(va.x);
        acc[2] += wA * bflo(va.y); acc[3] += wA * bfhi(va.y);
        acc[4] += wA * bflo(va.z); acc[5] += wA * bfhi(va.z);
        acc[6] += wA * bflo(va.w); acc[7] += wA * bfhi(va.w);
      }
    }
  } else {
    // ---- generic fallback: 3-pass with per-edge scratch (bf16 gather) ----
    float m = -INFINITY;
    for (int j = beg + lane; j < end; j += 64) {
      float e = al_s[csr_src[j]] + ald;
      e = (e > 0.f) ? e : 0.2f * e;
      exw[j] = e;
      m = fmaxf(m, e);
    }
    for (int off = 32; off; off >>= 1) m = fmaxf(m, __shfl_xor(m, off));

    float den = 0.f;
    for (int j = beg + lane; j < end; j += 64) {
      float ex = __expf(exw[j] - m);
      exw[j] = ex;
      den += ex;
    }
    for (int off = 32; off; off >>= 1) den += __shfl_xor(den, off);
    float inv = 1.0f / (den + 1e-16f);

    for (int j = beg + q; j < end; j += 4) {
      int sA = csr_src[j];
      float wA = exw[j] * inv;
      uint4 va = Hbf[(size_t)sA * 16 + l];
      acc[0] += wA * bflo(va.x); acc[1] += wA * bfhi(va.x);
      acc[2] += wA * bflo(va.y); acc[3] += wA * bfhi(va.y);
      acc[4] += wA * bflo(va.z); acc[5] += wA * bfhi(va.z);
      acc[6] += wA * bflo(va.w); acc[7] += wA * bfhi(va.w);
    }
  }

#pragma unroll
  for (int c = 0; c < 8; ++c) {
    acc[c] += __shfl_xor(acc[c], 16);
    acc[c] += __shfl_xor(acc[c], 32);
  }
  if (q == 0) {
    float4 bv0 = *(const float4*)(bias + l * 8);
    float4 bv1 = *(const float4*)(bias + l * 8 + 4);
    float o0 = acc[0] + bv0.x, o1 = acc[1] + bv0.y, o2 = acc[2] + bv0.z, o3 = acc[3] + bv0.w;
    float o4 = acc[4] + bv1.x, o5 = acc[5] + bv1.y, o6 = acc[6] + bv1.z, o7 = acc[7] + bv1.w;
    if (relu) {
      o0 = fmaxf(o0, 0.f); o1 = fmaxf(o1, 0.f); o2 = fmaxf(o2, 0.f); o3 = fmaxf(o3, 0.f);
      o4 = fmaxf(o4, 0.f); o5 = fmaxf(o5, 0.f); o6 = fmaxf(o6, 0.f); o7 = fmaxf(o7, 0.f);
    }
    uint4v pb;
    pb.x = pk2bf(o0, o1); pb.y = pk2bf(o2, o3);
    pb.z = pk2bf(o4, o5); pb.w = pk2bf(o6, o7);
    __builtin_nontemporal_store(pb, (uint4v*)(Ybf + (size_t)dst * 64 + l * 4));
  }
}

// run-length pooling over sorted batch, bf16 input (lane owns feats 2l,2l+1)
__global__ __launch_bounds__(256) void k_pool(const unsigned* __restrict__ Ybf,
                                              const int* __restrict__ batch,
                                              float* __restrict__ gsum,
                                              float* __restrict__ gcnt,
                                              int N, int nwaves) {
  int gw = (blockIdx.x * 256 + threadIdx.x) >> 6;
  int lane = threadIdx.x & 63;
  int chunk = (N + nwaves - 1) / nwaves;
  int beg = gw * chunk;
  int end = beg + chunk; if (end > N) end = N;
  if (beg >= end) return;

  int curg = batch[beg];
  float2 acc = {0.f, 0.f};
  int cnt = 0;
  for (int n = beg; n < end; ++n) {
    int g = batch[n];
    if (g != curg) {
      atomicAdd(&gsum[curg * 128 + lane * 2], acc.x);
      atomicAdd(&gsum[curg * 128 + lane * 2 + 1], acc.y);
      if (lane == 0) atomicAdd(&gcnt[curg], (float)cnt);
      acc.x = 0.f; acc.y = 0.f; cnt = 0; curg = g;
    }
    unsigned u = Ybf[(size_t)n * 64 + lane];
    acc.x += bflo(u); acc.y += bfhi(u);
    ++cnt;
  }
  atomicAdd(&gsum[curg * 128 + lane * 2], acc.x);
  atomicAdd(&gsum[curg * 128 + lane * 2 + 1], acc.y);
  if (lane == 0) atomicAdd(&gcnt[curg], (float)cnt);
}

__global__ __launch_bounds__(128) void k_final(const float* __restrict__ gsum,
                                               const float* __restrict__ gcnt,
                                               const float* __restrict__ Wlin,
                                               const float* __restrict__ blin,
                                               float* __restrict__ out) {
  int t = threadIdx.x;  // 128 threads: (g, c) pairs
  int g = t >> 1, c = t & 1;
  float inv = 1.0f / fmaxf(gcnt[g], 1.0f);
  float acc = blin[c];
  for (int k = 0; k < 128; ++k) acc += gsum[g * 128 + k] * inv * Wlin[k * 2 + c];
  out[g * 2 + c] = acc;
}

extern "C" void kernel_launch(void* const* d_in, const int* in_sizes, int n_in,
                              void* d_out, int out_size, void* d_ws, size_t ws_size,
                              hipStream_t stream) {
  const float* x    = (const float*)d_in[0];
  const int*   ei   = (const int*)d_in[1];
  const int*   batch= (const int*)d_in[2];
  const float* W1   = (const float*)d_in[3];
  const float* as1  = (const float*)d_in[4];
  const float* ad1  = (const float*)d_in[5];
  const float* b1   = (const float*)d_in[6];
  const float* W2   = (const float*)d_in[7];
  const float* as2  = (const float*)d_in[8];
  const float* ad2  = (const float*)d_in[9];
  const float* b2   = (const float*)d_in[10];
  const float* W3   = (const float*)d_in[11];
  const float* as3  = (const float*)d_in[12];
  const float* ad3  = (const float*)d_in[13];
  const float* b3   = (const float*)d_in[14];
  const float* Wlin = (const float*)d_in[15];
  const float* blin = (const float*)d_in[16];

  int N = in_sizes[0] / 4;
  int E = in_sizes[1] / 2;
  int ET = E + N;
  int NB = (N + BW - 1) / BW;   // buckets (<=128 for N<=65536)

  char* ws = (char*)d_ws;
  unsigned* bfA = (unsigned*)ws; ws += (size_t)N * 64 * 4;   // bf16 H table
  unsigned* bfB = (unsigned*)ws; ws += (size_t)N * 64 * 4;   // bf16 Y table
  float* al_s = (float*)ws; ws += (size_t)N * 4;
  float* al_d = (float*)ws; ws += (size_t)N * 4;
  float* wv   = (float*)ws; ws += (size_t)64 * 4;            // layer-1 al vecs
  float* gsum = (float*)ws; ws += (size_t)64 * 128 * 4;
  float* gcnt = (float*)ws; ws += (size_t)64 * 4;
  int* rowp   = (int*)ws;   ws += (size_t)(N + 1) * 4;
  int* csr    = (int*)ws;   ws += (size_t)ET * 4;
  float* exw  = (float*)ws; ws += (size_t)ET * 4;
  int* bucketed = (int*)ws; ws += (size_t)ET * 4;
  int* bpart  = (int*)ws;   ws += (size_t)HIST_WGS * 128 * 4;
  int* bbase  = (int*)ws;   ws += (size_t)132 * 4;
  int* bcur   = (int*)ws;   ws += (size_t)128 * 4;
  unsigned short* wcm2 = (unsigned short*)ws; ws += (size_t)128 * 128 * 2;
  unsigned short* wcm3 = (unsigned short*)ws; ws += (size_t)128 * 128 * 2;

  // CSR build (bucketed counting sort) + W prep/al1 + gsum zero (no memsets)
  kb_hist<<<HIST_WGS, 256, 0, stream>>>(ei, bpart, E, ET);
  kb_scan<<<1, 128, 0, stream>>>(bpart, bbase, bcur, rowp, N, ET, NB);
  kb_part<<<(ET + PART_CHUNK - 1) / PART_CHUNK, 256, 0, stream>>>(ei, bcur, bucketed, E, ET, NB);
  kb_csr <<<NB, 256, 0, stream>>>(bucketed, bbase, rowp, csr, N);
  k_prep <<<98, 256, 0, stream>>>(W2, W3, W1, as1, ad1, wcm2, wcm3, wv, gsum);

  int nb4 = (N + 3) / 4;
  int nb64 = (N + 63) / 64;
  // layer 1: fused al + gather-X + W1 tail
  k_aggx1<<<nb4, 256, 0, stream>>>(csr, rowp, wv, x, W1, b1, exw, bfB, N);
  // layer 2
  k_gemm128mfma<<<nb64, 256, 0, stream>>>((const unsigned short*)bfB, wcm2, as2, ad2, bfA, al_s, al_d, N);
  k_agg        <<<nb4, 256, 0, stream>>>(csr, rowp, al_s, al_d, (const uint4*)bfA, b2, exw, bfB, N, 1);
  // layer 3
  k_gemm128mfma<<<nb64, 256, 0, stream>>>((const unsigned short*)bfB, wcm3, as3, ad3, bfA, al_s, al_d, N);
  k_agg        <<<nb4, 256, 0, stream>>>(csr, rowp, al_s, al_d, (const uint4*)bfA, b3, exw, bfB, N, 0);

  // run-length pool (1024 waves) + linear head
  k_pool <<<256, 256, 0, stream>>>(bfB, batch, gsum, gcnt, N, 1024);
  k_final<<<1, 128, 0, stream>>>(gsum, gcnt, Wlin, blin, (float*)d_out);
}

// Round 11
// 308.010 us; speedup vs baseline: 1.1330x; 1.0147x over previous
//
#include <hip/hip_runtime.h>
#include <math.h>

// ---------------------------------------------------------------------------
// GAT 3-layer net. CSR by dst built once per call (bucketed counting sort).
// R1-R8: register softmax, bf16 gather table, counting-sort CSR build.
// R9: all-bf16 dataflow + MFMA for layers 2/3 (mfma_f32_16x16x32_bf16).
// R10: layer-1 algebraic restructure (gather raw X rows, L2-resident).
// R11: layer-3 bf16 out; k_aggx+W1-tail fusion; k_al1 in k_prep.
// R12: run-length k_pool restored.
// R13: partial-hist build (no memsets), gsum zero in prep, nt stores.
// R14: two dsts per wave in k_agg/k_aggx1 (deg<=32 covers ~99.97% of
//      nodes; mean deg 17 left half the wave idle in softmax/epilogue).
//      32-lane-half softmax; broadcast via (lane&32)+t+q selectors
//      (exec-uniform); alpha=0 padding for slots >= deg (no divergence);
//      rare deg>32 pairs take the original full-wave path. kb_csr+k_prep
//      merged; HIST_WGS 256->64. 12 -> 11 dispatches.
//      (R14b: nontemporal_store needs clang ext_vector types, not HIP's
//       uint2 class type -> custom uint2v.)
// ---------------------------------------------------------------------------

#define BW 512          // nodes per bucket (power of 2)
#define PART_CHUNK 4096 // edges per WG in kb_part
#define HIST_WGS 64     // kb_hist grid (partial buffer sized to match)

typedef __attribute__((ext_vector_type(8))) short short8v;  // 8 bf16
typedef __attribute__((ext_vector_type(4))) float f32x4;
typedef __attribute__((ext_vector_type(4))) unsigned uint4v;
typedef __attribute__((ext_vector_type(2))) unsigned uint2v;

__device__ __forceinline__ float bflo(unsigned u) { return __uint_as_float(u << 16); }
__device__ __forceinline__ float bfhi(unsigned u) { return __uint_as_float(u & 0xffff0000u); }
// pack two f32 -> two bf16 (round-nearest-even), a in low half, b in high
__device__ __forceinline__ unsigned pk2bf(float a, float b) {
  unsigned ua = __float_as_uint(a); ua += 0x7fffu + ((ua >> 16) & 1u);
  unsigned ub = __float_as_uint(b); ub += 0x7fffu + ((ub >> 16) & 1u);
  return (ua >> 16) | (ub & 0xffff0000u);
}

// ---- CSR build, stage 1: per-bucket counts -> per-WG partials ----
__global__ __launch_bounds__(256) void kb_hist(const int* __restrict__ ei,
                                               int* __restrict__ bpart,
                                               int E, int ET) {
  __shared__ int h[128];
  int tid = threadIdx.x;
  if (tid < 128) h[tid] = 0;
  __syncthreads();
  int stride = HIST_WGS * 256;
  for (int i = blockIdx.x * 256 + tid; i < ET; i += stride) {
    int dst = (i < E) ? ei[E + i] : (i - E);
    atomicAdd(&h[dst >> 9], 1);
  }
  __syncthreads();
  if (tid < 128) bpart[blockIdx.x * 128 + tid] = h[tid];
}

// ---- stage 2: 1 WG reduces partials + exclusive-scans NB (<=128) buckets ----
__global__ __launch_bounds__(128) void kb_scan(const int* __restrict__ bpart,
                                               int* __restrict__ bbase,
                                               int* __restrict__ bcur,
                                               int* __restrict__ rowp,
                                               int N, int ET, int NB) {
  __shared__ int sm[128];
  int t = threadIdx.x;
  int v = 0;
  for (int w = 0; w < HIST_WGS; ++w) v += bpart[w * 128 + t];  // coalesced
  if (t >= NB) v = 0;
  sm[t] = v;
  __syncthreads();
  for (int off = 1; off < 128; off <<= 1) {
    int u = (t >= off) ? sm[t - off] : 0;
    __syncthreads();
    sm[t] += u;
    __syncthreads();
  }
  int pre = sm[t] - v;                  // exclusive
  if (t <= NB) bbase[t] = pre;          // bbase[NB] == ET
  if (t < NB) bcur[t] = pre;
  if (t == 0) rowp[N] = ET;
}

// ---- stage 3: partition edges into bucket runs (packed src<<9|dstlocal) ----
__global__ __launch_bounds__(256) void kb_part(const int* __restrict__ ei,
                                               int* __restrict__ bcur,
                                               int* __restrict__ bucketed,
                                               int E, int ET, int NB) {
  __shared__ int hist[128];
  __shared__ int runb[128];
  int tid = threadIdx.x;
  int base = blockIdx.x * PART_CHUNK;
  if (tid < 128) hist[tid] = 0;

  int sv[16], dv[16];
#pragma unroll
  for (int k = 0; k < 16; ++k) {
    int j = base + k * 256 + tid;
    int s = -1, d = 0;
    if (j < ET) {
      if (j < E) { s = ei[j]; d = ei[E + j]; }
      else       { s = j - E; d = j - E; }
    }
    sv[k] = s; dv[k] = d;
  }
  __syncthreads();
#pragma unroll
  for (int k = 0; k < 16; ++k)
    if (sv[k] >= 0) atomicAdd(&hist[dv[k] >> 9], 1);
  __syncthreads();
  if (tid < NB && hist[tid] > 0) runb[tid] = atomicAdd(&bcur[tid], hist[tid]);
  __syncthreads();
  if (tid < 128) hist[tid] = 0;   // reuse as within-run cursor
  __syncthreads();
#pragma unroll
  for (int k = 0; k < 16; ++k) {
    if (sv[k] >= 0) {
      int b = dv[k] >> 9;
      int off = atomicAdd(&hist[b], 1);
      bucketed[runb[b] + off] = (sv[k] << 9) | (dv[k] & (BW - 1));
    }
  }
}

// ---- stage 4 + prep, merged. blocks [0,NB): per-bucket counting sort;
//      [NB,NB+64): bf16 col-major W2/W3; NB+64: layer-1 al vecs;
//      [NB+65,NB+98): zero gsum+gcnt ----
__global__ __launch_bounds__(256) void kb_csrprep(const int* __restrict__ bucketed,
                                                  const int* __restrict__ bbase,
                                                  int* __restrict__ rowp,
                                                  int* __restrict__ csr,
                                                  const float* __restrict__ W2,
                                                  const float* __restrict__ W3,
                                                  const float* __restrict__ W1,
                                                  const float* __restrict__ as1,
                                                  const float* __restrict__ ad1,
                                                  unsigned short* __restrict__ Wcm2,
                                                  unsigned short* __restrict__ Wcm3,
                                                  float* __restrict__ wv,
                                                  float* __restrict__ gsum,
                                                  int N, int NB) {
  int tid = threadIdx.x;
  if ((int)blockIdx.x >= NB) {
    int pb = blockIdx.x - NB;
    if (pb >= 65) {     // zero gsum (8192) + gcnt (64), contiguous
      int idx = (pb - 65) * 256 + tid;
      if (idx < 64 * 128 + 64) gsum[idx] = 0.f;
      return;
    }
    if (pb == 64) {     // wv[0..3]=W1@as1, wv[4..7]=W1@ad1
      if (tid >= 64) return;
      float2 a = *(const float2*)(as1 + tid * 2);
      float2 d = *(const float2*)(ad1 + tid * 2);
      float ps[4], pd[4];
#pragma unroll
      for (int k = 0; k < 4; ++k) {
        float2 w = *(const float2*)(W1 + k * 128 + tid * 2);
        ps[k] = w.x * a.x + w.y * a.y;
        pd[k] = w.x * d.x + w.y * d.y;
      }
      for (int off = 32; off; off >>= 1) {
#pragma unroll
        for (int k = 0; k < 4; ++k) {
          ps[k] += __shfl_xor(ps[k], off);
          pd[k] += __shfl_xor(pd[k], off);
        }
      }
      if (tid == 0) {
#pragma unroll
        for (int k = 0; k < 4; ++k) { wv[k] = ps[k]; wv[4 + k] = pd[k]; }
      }
      return;
    }
    int i = pb * 256 + tid;   // 16384 = 128*128
    if (i < 16384) {
      int k = i >> 7, n = i & 127;
      unsigned u = __float_as_uint(W2[i]); u += 0x7fffu + ((u >> 16) & 1u);
      Wcm2[n * 128 + k] = (unsigned short)(u >> 16);
      unsigned v = __float_as_uint(W3[i]); v += 0x7fffu + ((v >> 16) & 1u);
      Wcm3[n * 128 + k] = (unsigned short)(v >> 16);
    }
    return;
  }
  // per-bucket counting sort
  __shared__ int h[512];
  __shared__ int sm[256];
  __shared__ int cur[512];
  int b = blockIdx.x;
  int cb = bbase[b], ce = bbase[b + 1];

  h[tid] = 0; h[tid + 256] = 0;
  __syncthreads();
  for (int j = cb + tid; j < ce; j += 256)
    atomicAdd(&h[bucketed[j] & (BW - 1)], 1);
  __syncthreads();
  int a0 = h[2 * tid], a1 = h[2 * tid + 1];
  int s = a0 + a1;
  sm[tid] = s;
  __syncthreads();
  for (int off = 1; off < 256; off <<= 1) {
    int u = (tid >= off) ? sm[tid - off] : 0;
    __syncthreads();
    sm[tid] += u;
    __syncthreads();
  }
  int pre = sm[tid] - s;                 // exclusive over pairs
  cur[2 * tid] = pre;
  cur[2 * tid + 1] = pre + a0;
  __syncthreads();
  int node0 = b * BW;
  for (int local = tid; local < BW; local += 256) {
    int node = node0 + local;
    if (node < N) rowp[node] = cb + cur[local];   // coalesced segment write
  }
  __syncthreads();
  for (int j = cb + tid; j < ce; j += 256) {
    int p = bucketed[j];
    int loc = p & (BW - 1);
    int pos = cb + atomicAdd(&cur[loc], 1);
    csr[pos] = (unsigned)p >> 9;          // confined to [cb,ce) window
  }
}

// ---- full-wave (64-lane) fallback bodies, verbatim R13 logic ----
__device__ __forceinline__ void agg_full64(int beg, int end, float ald, int dst,
    const int* __restrict__ csr_src, const float* __restrict__ al_s,
    const uint4* __restrict__ Hbf, const float* __restrict__ bias,
    float* __restrict__ exw, unsigned* __restrict__ Ybf, int relu) {
  int lane = threadIdx.x & 63;
  int deg = end - beg;
  int q = lane >> 4, l = lane & 15;
  float acc[8];
#pragma unroll
  for (int c = 0; c < 8; ++c) acc[c] = 0.f;

  if (deg <= 64) {
    int srcv = 0;
    float e = -INFINITY;
    if (lane < deg) {
      srcv = csr_src[beg + lane];
      e = al_s[srcv] + ald;
      e = (e > 0.f) ? e : 0.2f * e;
    }
    float m = e;
    for (int off = 32; off; off >>= 1) m = fmaxf(m, __shfl_xor(m, off));
    float av = (lane < deg) ? __expf(e - m) : 0.f;
    float den = av;
    for (int off = 32; off; off >>= 1) den += __shfl_xor(den, off);
    av *= 1.0f / (den + 1e-16f);
    for (int t = 0; t < deg; t += 4) {      // padded slots have av=0
      int sA = __shfl(srcv, t + q);
      float wA = __shfl(av, t + q);
      uint4 va = Hbf[(size_t)sA * 16 + l];
      acc[0] += wA * bflo(va.x); acc[1] += wA * bfhi(va.x);
      acc[2] += wA * bflo(va.y); acc[3] += wA * bfhi(va.y);
      acc[4] += wA * bflo(va.z); acc[5] += wA * bfhi(va.z);
      acc[6] += wA * bflo(va.w); acc[7] += wA * bfhi(va.w);
    }
  } else {
    float m = -INFINITY;
    for (int j = beg + lane; j < end; j += 64) {
      float e = al_s[csr_src[j]] + ald;
      e = (e > 0.f) ? e : 0.2f * e;
      exw[j] = e;
      m = fmaxf(m, e);
    }
    for (int off = 32; off; off >>= 1) m = fmaxf(m, __shfl_xor(m, off));
    float den = 0.f;
    for (int j = beg + lane; j < end; j += 64) {
      float ex = __expf(exw[j] - m);
      exw[j] = ex;
      den += ex;
    }
    for (int off = 32; off; off >>= 1) den += __shfl_xor(den, off);
    float inv = 1.0f / (den + 1e-16f);
    for (int j = beg + q; j < end; j += 4) {
      int sA = csr_src[j];
      float wA = exw[j] * inv;
      uint4 va = Hbf[(size_t)sA * 16 + l];
      acc[0] += wA * bflo(va.x); acc[1] += wA * bfhi(va.x);
      acc[2] += wA * bflo(va.y); acc[3] += wA * bfhi(va.y);
      acc[4] += wA * bflo(va.z); acc[5] += wA * bfhi(va.z);
      acc[6] += wA * bflo(va.w); acc[7] += wA * bfhi(va.w);
    }
  }
#pragma unroll
  for (int c = 0; c < 8; ++c) {
    acc[c] += __shfl_xor(acc[c], 16);
    acc[c] += __shfl_xor(acc[c], 32);
  }
  if (q == 0) {
    float4 bv0 = *(const float4*)(bias + l * 8);
    float4 bv1 = *(const float4*)(bias + l * 8 + 4);
    float o0 = acc[0] + bv0.x, o1 = acc[1] + bv0.y, o2 = acc[2] + bv0.z, o3 = acc[3] + bv0.w;
    float o4 = acc[4] + bv1.x, o5 = acc[5] + bv1.y, o6 = acc[6] + bv1.z, o7 = acc[7] + bv1.w;
    if (relu) {
      o0 = fmaxf(o0, 0.f); o1 = fmaxf(o1, 0.f); o2 = fmaxf(o2, 0.f); o3 = fmaxf(o3, 0.f);
      o4 = fmaxf(o4, 0.f); o5 = fmaxf(o5, 0.f); o6 = fmaxf(o6, 0.f); o7 = fmaxf(o7, 0.f);
    }
    uint4v pb;
    pb.x = pk2bf(o0, o1); pb.y = pk2bf(o2, o3);
    pb.z = pk2bf(o4, o5); pb.w = pk2bf(o6, o7);
    __builtin_nontemporal_store(pb, (uint4v*)(Ybf + (size_t)dst * 64 + l * 4));
  }
}

__device__ __forceinline__ void aggx1_full64(int beg, int end, float ald, int dst,
    const int* __restrict__ csr_src, const float* __restrict__ X,
    float wvs0, float wvs1, float wvs2, float wvs3,
    const float* __restrict__ W, const float* __restrict__ bias,
    float* __restrict__ exw, unsigned* __restrict__ Ybf) {
  int lane = threadIdx.x & 63;
  int deg = end - beg;
  float4 acc = {0.f, 0.f, 0.f, 0.f};
  if (deg <= 64) {
    int srcv = 0;
    float e = -INFINITY;
    float4 xv = {0.f, 0.f, 0.f, 0.f};
    if (lane < deg) {
      srcv = csr_src[beg + lane];
      xv = *(const float4*)(X + (size_t)srcv * 4);
      e = xv.x * wvs0 + xv.y * wvs1 + xv.z * wvs2 + xv.w * wvs3 + ald;
      e = (e > 0.f) ? e : 0.2f * e;
    }
    float m = e;
    for (int off = 32; off; off >>= 1) m = fmaxf(m, __shfl_xor(m, off));
    float av = (lane < deg) ? __expf(e - m) : 0.f;
    float den = av;
    for (int off = 32; off; off >>= 1) den += __shfl_xor(den, off);
    av *= 1.0f / (den + 1e-16f);
    acc.x = av * xv.x; acc.y = av * xv.y; acc.z = av * xv.z; acc.w = av * xv.w;
  } else {
    float m = -INFINITY;
    for (int j = beg + lane; j < end; j += 64) {
      int s = csr_src[j];
      float4 xv = *(const float4*)(X + (size_t)s * 4);
      float e = xv.x * wvs0 + xv.y * wvs1 + xv.z * wvs2 + xv.w * wvs3 + ald;
      e = (e > 0.f) ? e : 0.2f * e;
      exw[j] = e;
      m = fmaxf(m, e);
    }
    for (int off = 32; off; off >>= 1) m = fmaxf(m, __shfl_xor(m, off));
    float den = 0.f;
    for (int j = beg + lane; j < end; j += 64) {
      float ex = __expf(exw[j] - m);
      exw[j] = ex;
      den += ex;
    }
    for (int off = 32; off; off >>= 1) den += __shfl_xor(den, off);
    float inv = 1.0f / (den + 1e-16f);
    for (int j = beg + lane; j < end; j += 64) {
      int s = csr_src[j];
      float w = exw[j] * inv;
      float4 xv = *(const float4*)(X + (size_t)s * 4);
      acc.x += w * xv.x; acc.y += w * xv.y; acc.z += w * xv.z; acc.w += w * xv.w;
    }
  }
  for (int off = 32; off; off >>= 1) {
    acc.x += __shfl_xor(acc.x, off);
    acc.y += __shfl_xor(acc.y, off);
    acc.z += __shfl_xor(acc.z, off);
    acc.w += __shfl_xor(acc.w, off);
  }
  int f = lane * 2;
  float2 w0 = *(const float2*)(W + f);
  float2 w1 = *(const float2*)(W + 128 + f);
  float2 w2 = *(const float2*)(W + 256 + f);
  float2 w3 = *(const float2*)(W + 384 + f);
  float2 bv = *(const float2*)(bias + f);
  float h0 = acc.x * w0.x + acc.y * w1.x + acc.z * w2.x + acc.w * w3.x + bv.x;
  float h1 = acc.x * w0.y + acc.y * w1.y + acc.z * w2.y + acc.w * w3.y + bv.y;
  h0 = fmaxf(h0, 0.f); h1 = fmaxf(h1, 0.f);
  __builtin_nontemporal_store(pk2bf(h0, h1), Ybf + (size_t)dst * 64 + lane);
}

// ---- layer-1 fused agg + tail gemm, TWO dsts per wave (deg<=32 wide path) ----
__global__ __launch_bounds__(256) void k_aggx1(const int* __restrict__ csr_src,
                                               const int* __restrict__ rowp,
                                               const float* __restrict__ wv,
                                               const float* __restrict__ X,
                                               const float* __restrict__ W,
                                               const float* __restrict__ bias,
                                               float* __restrict__ exw,
                                               unsigned* __restrict__ Ybf, int N) {
  int wid = threadIdx.x >> 6, lane = threadIdx.x & 63;
  int half = lane >> 5, il = lane & 31;
  int d0 = blockIdx.x * 8 + wid * 2;
  if (d0 >= N) return;
  float wvs0 = wv[0], wvs1 = wv[1], wvs2 = wv[2], wvs3 = wv[3];
  float wvd0 = wv[4], wvd1 = wv[5], wvd2 = wv[6], wvd3 = wv[7];

  int dst = d0 + half;
  bool vdst = dst < N;
  int beg = 0, end = 0;
  if (vdst) { beg = rowp[dst]; end = rowp[dst + 1]; }
  int deg = end - beg;
  int mx = max(deg, __shfl_xor(deg, 32));   // wave-uniform

  float ald = 0.f;
  if (vdst) {
    float4 xd = *(const float4*)(X + (size_t)dst * 4);
    ald = xd.x * wvd0 + xd.y * wvd1 + xd.z * wvd2 + xd.w * wvd3;
  }

  if (mx <= 32) {
    int srcv = 0;
    float e = -INFINITY;
    float4 xv = {0.f, 0.f, 0.f, 0.f};
    if (il < deg) {
      srcv = csr_src[beg + il];
      xv = *(const float4*)(X + (size_t)srcv * 4);
      float e0 = xv.x * wvs0 + xv.y * wvs1 + xv.z * wvs2 + xv.w * wvs3 + ald;
      e = (e0 > 0.f) ? e0 : 0.2f * e0;
    }
    float m = e;
    for (int off = 16; off; off >>= 1) m = fmaxf(m, __shfl_xor(m, off));
    float av = (il < deg) ? __expf(e - m) : 0.f;
    float den = av;
    for (int off = 16; off; off >>= 1) den += __shfl_xor(den, off);
    av *= 1.0f / (den + 1e-16f);
    float4 acc;
    acc.x = av * xv.x; acc.y = av * xv.y; acc.z = av * xv.z; acc.w = av * xv.w;
    for (int off = 16; off; off >>= 1) {   // reduce within half
      acc.x += __shfl_xor(acc.x, off);
      acc.y += __shfl_xor(acc.y, off);
      acc.z += __shfl_xor(acc.z, off);
      acc.w += __shfl_xor(acc.w, off);
    }
    // tail gemm: half's 32 lanes each produce 4 of 128 features
    int f = il * 4;
    float4 w0 = *(const float4*)(W + f);
    float4 w1 = *(const float4*)(W + 128 + f);
    float4 w2 = *(const float4*)(W + 256 + f);
    float4 w3 = *(const float4*)(W + 384 + f);
    float4 bv = *(const float4*)(bias + f);
    float h0 = acc.x * w0.x + acc.y * w1.x + acc.z * w2.x + acc.w * w3.x + bv.x;
    float h1 = acc.x * w0.y + acc.y * w1.y + acc.z * w2.y + acc.w * w3.y + bv.y;
    float h2 = acc.x * w0.z + acc.y * w1.z + acc.z * w2.z + acc.w * w3.z + bv.z;
    float h3 = acc.x * w0.w + acc.y * w1.w + acc.z * w2.w + acc.w * w3.w + bv.w;
    h0 = fmaxf(h0, 0.f); h1 = fmaxf(h1, 0.f);
    h2 = fmaxf(h2, 0.f); h3 = fmaxf(h3, 0.f);
    if (vdst) {
      uint2v pb;
      pb.x = pk2bf(h0, h1); pb.y = pk2bf(h2, h3);
      __builtin_nontemporal_store(pb, (uint2v*)(Ybf + (size_t)dst * 64 + il * 2));
    }
  } else {
    for (int k = 0; k < 2; ++k) {          // rare: full-wave per dst
      int d = d0 + k;
      if (d < N) {
        int b = rowp[d], en = rowp[d + 1];
        float4 xd = *(const float4*)(X + (size_t)d * 4);
        float a2 = xd.x * wvd0 + xd.y * wvd1 + xd.z * wvd2 + xd.w * wvd3;
        aggx1_full64(b, en, a2, d, csr_src, X, wvs0, wvs1, wvs2, wvs3, W, bias, exw, Ybf);
      }
    }
  }
}

// MFMA GEMM: Xbf [N,128] bf16 @ Wcm [128,128] bf16 (col-major) -> Hbf bf16,
// fused al epilogue. One wave per 16 rows; 8 col-frags x 4 k-tiles of
// mfma_f32_16x16x32_bf16. C layout: col=lane&15, row=(lane>>4)*4+reg.
__global__ __launch_bounds__(256) void k_gemm128mfma(
    const unsigned short* __restrict__ Xbf,
    const unsigned short* __restrict__ Wcm,
    const float* __restrict__ asv, const float* __restrict__ adv,
    unsigned* __restrict__ Hbf,
    float* __restrict__ al_s, float* __restrict__ al_d, int N) {
  int wid = threadIdx.x >> 6, lane = threadIdx.x & 63;
  int c = lane & 15, g = lane >> 4;
  int row0 = blockIdx.x * 64 + wid * 16;
  int arow = row0 + c;
  int arowc = (arow < N) ? arow : (N - 1);

  short8v a[4];
#pragma unroll
  for (int kt = 0; kt < 4; ++kt)
    a[kt] = *(const short8v*)(Xbf + (size_t)arowc * 128 + kt * 32 + g * 8);

  f32x4 acc[8];
#pragma unroll
  for (int f = 0; f < 8; ++f) acc[f] = (f32x4){0.f, 0.f, 0.f, 0.f};

#pragma unroll
  for (int f = 0; f < 8; ++f) {
    const unsigned short* wb = Wcm + (size_t)(f * 16 + c) * 128 + g * 8;
#pragma unroll
    for (int kt = 0; kt < 4; ++kt) {
      short8v b = *(const short8v*)(wb + kt * 32);
      acc[f] = __builtin_amdgcn_mfma_f32_16x16x32_bf16(a[kt], b, acc[f], 0, 0, 0);
    }
  }

  // al epilogue: ps/pd per row, reduce across the 16 col-lanes
  float ps[4] = {0.f, 0.f, 0.f, 0.f}, pd[4] = {0.f, 0.f, 0.f, 0.f};
#pragma unroll
  for (int f = 0; f < 8; ++f) {
    float as_c = asv[f * 16 + c], ad_c = adv[f * 16 + c];
#pragma unroll
    for (int j = 0; j < 4; ++j) { ps[j] += acc[f][j] * as_c; pd[j] += acc[f][j] * ad_c; }
  }
#pragma unroll
  for (int j = 0; j < 4; ++j) {
    for (int off = 1; off < 16; off <<= 1) {
      ps[j] += __shfl_xor(ps[j], off);
      pd[j] += __shfl_xor(pd[j], off);
    }
  }
  if (c == 0) {
#pragma unroll
    for (int j = 0; j < 4; ++j) {
      int r = row0 + g * 4 + j;
      if (r < N) { al_s[r] = ps[j]; al_d[r] = pd[j]; }
    }
  }

  // bf16 store: pair adjacent cols via shfl (uniform exec), even lanes store u32
#pragma unroll
  for (int f = 0; f < 8; ++f) {
#pragma unroll
    for (int j = 0; j < 4; ++j) {
      float partner = __shfl_xor(acc[f][j], 1);
      int r = row0 + g * 4 + j;
      if (((lane & 1) == 0) && r < N)
        __builtin_nontemporal_store(pk2bf(acc[f][j], partner),
                                    Hbf + (size_t)r * 64 + f * 8 + (c >> 1));
    }
  }
}

// per-dst softmax + aggregation, TWO dsts per wave (deg<=32 wide path).
// Each 32-lane half: register softmax; gather 2 quarters (16B/lane/edge),
// 8 edges per iter (4 lines in flight); alpha=0 pads slots >= deg.
// Rare deg>32 pairs: original full-wave path per dst. bf16 Y out (nt).
__global__ __launch_bounds__(256) void k_agg(const int* __restrict__ csr_src,
                                             const int* __restrict__ rowp,
                                             const float* __restrict__ al_s,
                                             const float* __restrict__ al_d,
                                             const uint4* __restrict__ Hbf,
                                             const float* __restrict__ bias,
                                             float* __restrict__ exw,
                                             unsigned* __restrict__ Ybf,
                                             int N, int relu) {
  int wid = threadIdx.x >> 6, lane = threadIdx.x & 63;
  int half = lane >> 5, il = lane & 31;
  int d0 = blockIdx.x * 8 + wid * 2;
  if (d0 >= N) return;
  int dst = d0 + half;
  bool vdst = dst < N;
  int beg = 0, end = 0;
  if (vdst) { beg = rowp[dst]; end = rowp[dst + 1]; }
  int deg = end - beg;
  int mx = max(deg, __shfl_xor(deg, 32));   // wave-uniform
  float ald = vdst ? al_d[dst] : 0.f;

  if (mx <= 32) {
    int srcv = 0;
    float e = -INFINITY;
    if (il < deg) {
      srcv = csr_src[beg + il];
      e = al_s[srcv] + ald;
      e = (e > 0.f) ? e : 0.2f * e;
    }
    float m = e;
    for (int off = 16; off; off >>= 1) m = fmaxf(m, __shfl_xor(m, off));
    float av = (il < deg) ? __expf(e - m) : 0.f;
    float den = av;
    for (int off = 16; off; off >>= 1) den += __shfl_xor(den, off);
    av *= 1.0f / (den + 1e-16f);   // alpha (0 for padded slots)

    int q = il >> 4, l = il & 15;
    int b32 = lane & 32;
    float acc[8];
#pragma unroll
    for (int c = 0; c < 8; ++c) acc[c] = 0.f;

    for (int t = 0; t < mx; t += 8) {   // 8 edges/half/iter, alpha-0 padded
      int s0 = __shfl(srcv, b32 + t + q);
      int s1 = __shfl(srcv, b32 + t + 2 + q);
      int s2 = __shfl(srcv, b32 + t + 4 + q);
      int s3 = __shfl(srcv, b32 + t + 6 + q);
      float w0 = __shfl(av, b32 + t + q);
      float w1 = __shfl(av, b32 + t + 2 + q);
      float w2 = __shfl(av, b32 + t + 4 + q);
      float w3 = __shfl(av, b32 + t + 6 + q);
      uint4 v0 = Hbf[(size_t)s0 * 16 + l];
      uint4 v1 = Hbf[(size_t)s1 * 16 + l];
      uint4 v2 = Hbf[(size_t)s2 * 16 + l];
      uint4 v3 = Hbf[(size_t)s3 * 16 + l];
      acc[0] += w0 * bflo(v0.x) + w1 * bflo(v1.x) + w2 * bflo(v2.x) + w3 * bflo(v3.x);
      acc[1] += w0 * bfhi(v0.x) + w1 * bfhi(v1.x) + w2 * bfhi(v2.x) + w3 * bfhi(v3.x);
      acc[2] += w0 * bflo(v0.y) + w1 * bflo(v1.y) + w2 * bflo(v2.y) + w3 * bflo(v3.y);
      acc[3] += w0 * bfhi(v0.y) + w1 * bfhi(v1.y) + w2 * bfhi(v2.y) + w3 * bfhi(v3.y);
      acc[4] += w0 * bflo(v0.z) + w1 * bflo(v1.z) + w2 * bflo(v2.z) + w3 * bflo(v3.z);
      acc[5] += w0 * bfhi(v0.z) + w1 * bfhi(v1.z) + w2 * bfhi(v2.z) + w3 * bfhi(v3.z);
      acc[6] += w0 * bflo(v0.w) + w1 * bflo(v1.w) + w2 * bflo(v2.w) + w3 * bflo(v3.w);
      acc[7] += w0 * bfhi(v0.w) + w1 * bfhi(v1.w) + w2 * bfhi(v2.w) + w3 * bfhi(v3.w);
    }
#pragma unroll
    for (int c = 0; c < 8; ++c) acc[c] += __shfl_xor(acc[c], 16);  // quarters
    if (q == 0 && vdst) {
      float4 bv0 = *(const float4*)(bias + l * 8);
      float4 bv1 = *(const float4*)(bias + l * 8 + 4);
      float o0 = acc[0] + bv0.x, o1 = acc[1] + bv0.y, o2 = acc[2] + bv0.z, o3 = acc[3] + bv0.w;
      float o4 = acc[4] + bv1.x, o5 = acc[5] + bv1.y, o6 = acc[6] + bv1.z, o7 = acc[7] + bv1.w;
      if (relu) {
        o0 = fmaxf(o0, 0.f); o1 = fmaxf(o1, 0.f); o2 = fmaxf(o2, 0.f); o3 = fmaxf(o3, 0.f);
        o4 = fmaxf(o4, 0.f); o5 = fmaxf(o5, 0.f); o6 = fmaxf(o6, 0.f); o7 = fmaxf(o7, 0.f);
      }
      uint4v pb;
      pb.x = pk2bf(o0, o1); pb.y = pk2bf(o2, o3);
      pb.z = pk2bf(o4, o5); pb.w = pk2bf(o6, o7);
      __builtin_nontemporal_store(pb, (uint4v*)(Ybf + (size_t)dst * 64 + l * 4));
    }
  } else {
    for (int k = 0; k < 2; ++k) {          // rare: full-wave per dst
      int d = d0 + k;
      if (d < N) {
        int b = rowp[d], en = rowp[d + 1];
        agg_full64(b, en, al_d[d], d, csr_src, al_s, Hbf, bias, exw, Ybf, relu);
      }
    }
  }
}

// run-length pooling over sorted batch, bf16 input (lane owns feats 2l,2l+1)
__global__ __launch_bounds__(256) void k_pool(const unsigned* __restrict__ Ybf,
                                              const int* __restrict__ batch,
                                              float* __restrict__ gsum,
                                              float* __restrict__ gcnt,
                                              int N, int nwaves) {
  int gw = (blockIdx.x * 256 + threadIdx.x) >> 6;
  int lane = threadIdx.x & 63;
  int chunk = (N + nwaves - 1) / nwaves;
  int beg = gw * chunk;
  int end = beg + chunk; if (end > N) end = N;
  if (beg >= end) return;

  int curg = batch[beg];
  float2 acc = {0.f, 0.f};
  int cnt = 0;
  for (int n = beg; n < end; ++n) {
    int g = batch[n];
    if (g != curg) {
      atomicAdd(&gsum[curg * 128 + lane * 2], acc.x);
      atomicAdd(&gsum[curg * 128 + lane * 2 + 1], acc.y);
      if (lane == 0) atomicAdd(&gcnt[curg], (float)cnt);
      acc.x = 0.f; acc.y = 0.f; cnt = 0; curg = g;
    }
    unsigned u = Ybf[(size_t)n * 64 + lane];
    acc.x += bflo(u); acc.y += bfhi(u);
    ++cnt;
  }
  atomicAdd(&gsum[curg * 128 + lane * 2], acc.x);
  atomicAdd(&gsum[curg * 128 + lane * 2 + 1], acc.y);
  if (lane == 0) atomicAdd(&gcnt[curg], (float)cnt);
}

__global__ __launch_bounds__(128) void k_final(const float* __restrict__ gsum,
                                               const float* __restrict__ gcnt,
                                               const float* __restrict__ Wlin,
                                               const float* __restrict__ blin,
                                               float* __restrict__ out) {
  int t = threadIdx.x;  // 128 threads: (g, c) pairs
  int g = t >> 1, c = t & 1;
  float inv = 1.0f / fmaxf(gcnt[g], 1.0f);
  float acc = blin[c];
  for (int k = 0; k < 128; ++k) acc += gsum[g * 128 + k] * inv * Wlin[k * 2 + c];
  out[g * 2 + c] = acc;
}

extern "C" void kernel_launch(void* const* d_in, const int* in_sizes, int n_in,
                              void* d_out, int out_size, void* d_ws, size_t ws_size,
                              hipStream_t stream) {
  const float* x    = (const float*)d_in[0];
  const int*   ei   = (const int*)d_in[1];
  const int*   batch= (const int*)d_in[2];
  const float* W1   = (const float*)d_in[3];
  const float* as1  = (const float*)d_in[4];
  const float* ad1  = (const float*)d_in[5];
  const float* b1   = (const float*)d_in[6];
  const float* W2   = (const float*)d_in[7];
  const float* as2  = (const float*)d_in[8];
  const float* ad2  = (const float*)d_in[9];
  const float* b2   = (const float*)d_in[10];
  const float* W3   = (const float*)d_in[11];
  const float* as3  = (const float*)d_in[12];
  const float* ad3  = (const float*)d_in[13];
  const float* b3   = (const float*)d_in[14];
  const float* Wlin = (const float*)d_in[15];
  const float* blin = (const float*)d_in[16];

  int N = in_sizes[0] / 4;
  int E = in_sizes[1] / 2;
  int ET = E + N;
  int NB = (N + BW - 1) / BW;   // buckets (<=128 for N<=65536)

  char* ws = (char*)d_ws;
  unsigned* bfA = (unsigned*)ws; ws += (size_t)N * 64 * 4;   // bf16 H table
  unsigned* bfB = (unsigned*)ws; ws += (size_t)N * 64 * 4;   // bf16 Y table
  float* al_s = (float*)ws; ws += (size_t)N * 4;
  float* al_d = (float*)ws; ws += (size_t)N * 4;
  float* wv   = (float*)ws; ws += (size_t)64 * 4;            // layer-1 al vecs
  float* gsum = (float*)ws; ws += (size_t)64 * 128 * 4;
  float* gcnt = (float*)ws; ws += (size_t)64 * 4;
  int* rowp   = (int*)ws;   ws += (size_t)(N + 1) * 4;
  int* csr    = (int*)ws;   ws += (size_t)ET * 4;
  float* exw  = (float*)ws; ws += (size_t)ET * 4;
  int* bucketed = (int*)ws; ws += (size_t)ET * 4;
  int* bpart  = (int*)ws;   ws += (size_t)HIST_WGS * 128 * 4;
  int* bbase  = (int*)ws;   ws += (size_t)132 * 4;
  int* bcur   = (int*)ws;   ws += (size_t)128 * 4;
  unsigned short* wcm2 = (unsigned short*)ws; ws += (size_t)128 * 128 * 2;
  unsigned short* wcm3 = (unsigned short*)ws; ws += (size_t)128 * 128 * 2;

  // CSR build (bucketed counting sort) + merged prep (no memsets)
  kb_hist<<<HIST_WGS, 256, 0, stream>>>(ei, bpart, E, ET);
  kb_scan<<<1, 128, 0, stream>>>(bpart, bbase, bcur, rowp, N, ET, NB);
  kb_part<<<(ET + PART_CHUNK - 1) / PART_CHUNK, 256, 0, stream>>>(ei, bcur, bucketed, E, ET, NB);
  kb_csrprep<<<NB + 98, 256, 0, stream>>>(bucketed, bbase, rowp, csr,
                                          W2, W3, W1, as1, ad1, wcm2, wcm3, wv, gsum, N, NB);

  int nb8 = (N + 7) / 8;
  int nb64 = (N + 63) / 64;
  // layer 1: fused al + gather-X + W1 tail (2 dsts/wave)
  k_aggx1<<<nb8, 256, 0, stream>>>(csr, rowp, wv, x, W1, b1, exw, bfB, N);
  // layer 2
  k_gemm128mfma<<<nb64, 256, 0, stream>>>((const unsigned short*)bfB, wcm2, as2, ad2, bfA, al_s, al_d, N);
  k_agg        <<<nb8, 256, 0, stream>>>(csr, rowp, al_s, al_d, (const uint4*)bfA, b2, exw, bfB, N, 1);
  // layer 3
  k_gemm128mfma<<<nb64, 256, 0, stream>>>((const unsigned short*)bfB, wcm3, as3, ad3, bfA, al_s, al_d, N);
  k_agg        <<<nb8, 256, 0, stream>>>(csr, rowp, al_s, al_d, (const uint4*)bfA, b3, exw, bfB, N, 0);

  // run-length pool (1024 waves) + linear head
  k_pool <<<256, 256, 0, stream>>>(bfB, batch, gsum, gcnt, N, 1024);
  k_final<<<1, 128, 0, stream>>>(gsum, gcnt, Wlin, blin, (float*)d_out);
}